// Round 1
// baseline (1093.658 us; speedup 1.0000x reference)
//
#include <hip/hip_runtime.h>
#include <hip/hip_bf16.h>
#include <cstddef>
#include <cstdint>

// Problem constants
#define BB 2
#define HH 128
#define WW 128
#define CC 256
#define WSZ 8
#define KWIN 16
#define NHEADS 8
#define HD 32
#define C3 768
#define NPIX 32768            // B*H*W
#define NWIN 512              // B * 16 * 16

// ---------------------------------------------------------------------------
// CPB MLP: bias_tab[529][8] = sigmoid(relu(tab @ w1 + b1) @ w2) * 16
// grid 529, block 64
// ---------------------------------------------------------------------------
__global__ __launch_bounds__(64) void cpb_kernel(const float* __restrict__ w1,
                                                 const float* __restrict__ b1,
                                                 const float* __restrict__ w2,
                                                 float* __restrict__ btab) {
    const int e = blockIdx.x;          // 0..528
    const int i = e / 23, j = e % 23;
    const float inv_log8 = 1.0f / logf(8.0f);
    float c0 = (float)(i - 11) * (8.0f / 7.0f);
    float c1 = (float)(j - 11) * (8.0f / 7.0f);
    float f0 = copysignf(log1pf(fabsf(c0)) * inv_log8, c0);
    float f1 = copysignf(log1pf(fabsf(c1)) * inv_log8, c1);

    const int t = threadIdx.x;
    float acc[8] = {0.f,0.f,0.f,0.f,0.f,0.f,0.f,0.f};
    for (int kk = 0; kk < 8; kk++) {
        int k = kk * 64 + t;
        float hid = f0 * w1[k] + f1 * w1[512 + k] + b1[k];
        hid = fmaxf(hid, 0.f);
        #pragma unroll
        for (int h = 0; h < 8; h++) acc[h] += hid * w2[k * 8 + h];
    }
    #pragma unroll
    for (int h = 0; h < 8; h++) {
        #pragma unroll
        for (int off = 32; off >= 1; off >>= 1) acc[h] += __shfl_xor(acc[h], off);
    }
    if (t < 8) {
        float v = acc[t];
        btab[e * 8 + t] = 16.0f / (1.0f + expf(-v));
    }
}

// ---------------------------------------------------------------------------
// fp32 GEMM: C[M,N] = A[M,K] @ B[K,N], row-major. M%64==0, N%64==0, K%16==0.
// 64x64 tile, 256 threads, 4x4 per thread.
// ---------------------------------------------------------------------------
__global__ __launch_bounds__(256) void gemm_f32(const float* __restrict__ A,
                                                const float* __restrict__ B,
                                                float* __restrict__ C,
                                                int M, int N, int K) {
    __shared__ float As[16][65];   // [k][m], padded
    __shared__ float Bs[16][64];   // [k][n]
    const int tid = threadIdx.x;
    const int tx = tid & 15;       // col group (4 cols each)
    const int ty = tid >> 4;       // row group (4 rows each)
    const int rowb = blockIdx.y * 64;
    const int colb = blockIdx.x * 64;

    float acc[4][4] = {};
    for (int k0 = 0; k0 < K; k0 += 16) {
        {   // A tile: 64 rows x 16 k
            int r = tid >> 2;
            int c = (tid & 3) * 4;
            const float4 a4 = *(const float4*)(A + (size_t)(rowb + r) * K + k0 + c);
            As[c + 0][r] = a4.x; As[c + 1][r] = a4.y;
            As[c + 2][r] = a4.z; As[c + 3][r] = a4.w;
        }
        {   // B tile: 16 k x 64 cols
            int kr = tid >> 4;
            int cc = (tid & 15) * 4;
            *(float4*)&Bs[kr][cc] =
                *(const float4*)(B + (size_t)(k0 + kr) * N + colb + cc);
        }
        __syncthreads();
        #pragma unroll
        for (int kk = 0; kk < 16; kk++) {
            float a[4], b[4];
            #pragma unroll
            for (int ii = 0; ii < 4; ii++) a[ii] = As[kk][ty * 4 + ii];
            #pragma unroll
            for (int jj = 0; jj < 4; jj++) b[jj] = Bs[kk][tx * 4 + jj];
            #pragma unroll
            for (int ii = 0; ii < 4; ii++)
                #pragma unroll
                for (int jj = 0; jj < 4; jj++)
                    acc[ii][jj] += a[ii] * b[jj];
        }
        __syncthreads();
    }
    #pragma unroll
    for (int ii = 0; ii < 4; ii++) {
        float4 o = make_float4(acc[ii][0], acc[ii][1], acc[ii][2], acc[ii][3]);
        *(float4*)(C + (size_t)(rowb + ty * 4 + ii) * N + colb + tx * 4) = o;
    }
}

// ---------------------------------------------------------------------------
// Depthwise 3x3 conv (SAME, cross-correlation) + LayerNorm(768) + qkv bias add
// grid NPIX, block 256 (3 channels per thread)
// ---------------------------------------------------------------------------
__global__ __launch_bounds__(256) void dwconv_ln(const float* __restrict__ in,
                                                 const float* __restrict__ wdw,
                                                 const float* __restrict__ g,
                                                 const float* __restrict__ bt,
                                                 const float* __restrict__ qb,
                                                 const float* __restrict__ vb,
                                                 float* __restrict__ out) {
    const int pix = blockIdx.x;
    const int b = pix >> 14, y = (pix >> 7) & 127, x = pix & 127;
    const int t = threadIdx.x;

    float v[3];
    #pragma unroll
    for (int i = 0; i < 3; i++) {
        const int c = t + i * 256;
        float s = 0.f;
        #pragma unroll
        for (int dy = -1; dy <= 1; dy++) {
            int yy = y + dy;
            if (yy < 0 || yy > 127) continue;
            #pragma unroll
            for (int dx = -1; dx <= 1; dx++) {
                int xx = x + dx;
                if (xx < 0 || xx > 127) continue;
                s += in[(((size_t)b * 128 + yy) * 128 + xx) * C3 + c] *
                     wdw[((dy + 1) * 3 + (dx + 1)) * C3 + c];
            }
        }
        v[i] = s;
    }

    float ls  = v[0] + v[1] + v[2];
    float lss = v[0] * v[0] + v[1] * v[1] + v[2] * v[2];
    #pragma unroll
    for (int off = 32; off >= 1; off >>= 1) {
        ls  += __shfl_xor(ls, off);
        lss += __shfl_xor(lss, off);
    }
    __shared__ float sred[8];
    const int wave = t >> 6;
    if ((t & 63) == 0) { sred[wave * 2] = ls; sred[wave * 2 + 1] = lss; }
    __syncthreads();
    float S  = sred[0] + sred[2] + sred[4] + sred[6];
    float SS = sred[1] + sred[3] + sred[5] + sred[7];
    float mu  = S * (1.0f / 768.0f);
    float var = SS * (1.0f / 768.0f) - mu * mu;
    float rs  = rsqrtf(var + 1e-5f);

    const size_t base = (size_t)pix * C3;
    #pragma unroll
    for (int i = 0; i < 3; i++) {
        const int c = t + i * 256;
        float extra = (c < 256) ? qb[c] : ((c < 512) ? 0.f : vb[c - 512]);
        out[base + c] = (v[i] - mu) * rs * g[c] + bt[c] + extra;
    }
}

// ---------------------------------------------------------------------------
// Halo window attention. One block = (window, head), 64 threads (1 wave),
// one q row per lane. Flash-style over 8 chunks of 32 keys; shifted softmax
// with static max M = scale + 16 (exact; no underflow since s_max-M >= -36).
// ---------------------------------------------------------------------------
__global__ __launch_bounds__(64) void attn_kernel(const float* __restrict__ qkv,
                                                  const float* __restrict__ bias_tab,
                                                  const float* __restrict__ logit_scale,
                                                  float* __restrict__ out) {
    const int blk = blockIdx.x;
    const int h = blk & 7;
    const int wid = blk >> 3;                 // 0..511
    const int b = wid >> 8;
    const int wy = (wid >> 4) & 15;
    const int wx = wid & 15;
    const int t = threadIdx.x;                // q row 0..63
    const int qr = t >> 3, qc = t & 7;
    const int qy = wy * 8 + qr, qx = wx * 8 + qc;

    // load + l2-normalize + scale the q row (registers)
    const float* qptr = qkv + (((size_t)(b * 128 + qy) * 128 + qx) * C3) + h * HD;
    float qn[HD];
    float ssum = 0.f;
    #pragma unroll
    for (int d4 = 0; d4 < HD; d4 += 4) {
        float4 q4 = *(const float4*)(qptr + d4);
        qn[d4] = q4.x; qn[d4 + 1] = q4.y; qn[d4 + 2] = q4.z; qn[d4 + 3] = q4.w;
        ssum += q4.x * q4.x + q4.y * q4.y + q4.z * q4.z + q4.w * q4.w;
    }
    const float scale = expf(fminf(logit_scale[h], logf(100.f)));
    const float rn = rsqrtf(fmaxf(ssum, 1.55e-5f)) * scale;
    #pragma unroll
    for (int d = 0; d < HD; d++) qn[d] *= rn;

    __shared__ float btab[529];
    for (int e = t; e < 529; e += 64) btab[e] = bias_tab[e * 8 + h];

    __shared__ float kc[32][33];
    __shared__ float vc[32][33];

    const float M = scale + 16.0f;
    float l = 0.f;
    float acc[HD] = {};

    for (int j0 = 0; j0 < 256; j0 += 32) {
        __syncthreads();
        // stage 32 keys (k and v), zero-filled outside the image
        for (int f = t; f < 256; f += 64) {
            int jl = f >> 3, d = (f & 7) * 4;
            int j = j0 + jl;
            int kr = j >> 4, kcc = j & 15;
            int gy = wy * 8 - 4 + kr, gx = wx * 8 - 4 + kcc;
            float4 kk = {0.f, 0.f, 0.f, 0.f}, vv = {0.f, 0.f, 0.f, 0.f};
            if ((unsigned)gy < 128u && (unsigned)gx < 128u) {
                const float* p = qkv + (((size_t)(b * 128 + gy) * 128 + gx) * C3)
                               + 256 + h * HD + d;
                kk = *(const float4*)p;
                vv = *(const float4*)(p + 256);
            }
            kc[jl][d] = kk.x; kc[jl][d + 1] = kk.y; kc[jl][d + 2] = kk.z; kc[jl][d + 3] = kk.w;
            vc[jl][d] = vv.x; vc[jl][d + 1] = vv.y; vc[jl][d + 2] = vv.z; vc[jl][d + 3] = vv.w;
        }
        __syncthreads();
        // l2-normalize the 32 staged k rows
        if (t < 32) {
            float s2 = 0.f;
            #pragma unroll
            for (int d = 0; d < HD; d++) s2 += kc[t][d] * kc[t][d];
            float r = rsqrtf(fmaxf(s2, 1.55e-5f));
            #pragma unroll
            for (int d = 0; d < HD; d++) kc[t][d] *= r;
        }
        __syncthreads();
        // scores + shifted-softmax accumulate
        for (int jl = 0; jl < 32; jl++) {
            int j = j0 + jl;
            int kr = j >> 4, kcc = j & 15;
            float s = btab[(qr - kr + 15) * 23 + (qc - kcc + 15)];
            #pragma unroll
            for (int d = 0; d < HD; d++) s += qn[d] * kc[jl][d];
            float p = __expf(s - M);
            l += p;
            #pragma unroll
            for (int d = 0; d < HD; d++) acc[d] += p * vc[jl][d];
        }
    }

    const float inv = 1.0f / l;
    float* op = out + (((size_t)(b * 128 + qy) * 128 + qx) * CC) + h * HD;
    #pragma unroll
    for (int d4 = 0; d4 < HD; d4 += 4) {
        float4 o = make_float4(acc[d4] * inv, acc[d4 + 1] * inv,
                               acc[d4 + 2] * inv, acc[d4 + 3] * inv);
        *(float4*)(op + d4) = o;
    }
}

// ---------------------------------------------------------------------------
extern "C" void kernel_launch(void* const* d_in, const int* in_sizes, int n_in,
                              void* d_out, int out_size, void* d_ws, size_t ws_size,
                              hipStream_t stream) {
    const float* x           = (const float*)d_in[0];
    const float* w_qkv       = (const float*)d_in[1];
    const float* w_dw        = (const float*)d_in[2];
    const float* ln_g        = (const float*)d_in[3];
    const float* ln_b        = (const float*)d_in[4];
    const float* q_bias      = (const float*)d_in[5];
    const float* v_bias      = (const float*)d_in[6];
    const float* logit_scale = (const float*)d_in[7];
    const float* cpb_w1      = (const float*)d_in[8];
    const float* cpb_b1      = (const float*)d_in[9];
    const float* cpb_w2      = (const float*)d_in[10];
    const float* w_proj      = (const float*)d_in[11];
    float* out = (float*)d_out;

    char* ws = (char*)d_ws;
    const size_t BUF_BYTES = (size_t)NPIX * C3 * sizeof(float);   // 96 MB
    float* buf1 = (float*)ws;                       // qkv0, later attn out
    float* buf2 = (float*)(ws + BUF_BYTES);         // qkv post conv+LN
    float* btab = (float*)(ws + 2 * BUF_BYTES);     // 529*8 bias table

    // 1. CPB relative-bias table
    cpb_kernel<<<529, 64, 0, stream>>>(cpb_w1, cpb_b1, cpb_w2, btab);
    // 2. qkv0 = x @ w_qkv   (32768x256 @ 256x768)
    gemm_f32<<<dim3(C3 / 64, NPIX / 64), 256, 0, stream>>>(x, w_qkv, buf1,
                                                           NPIX, C3, CC);
    // 3. depthwise 3x3 + LN + bias
    dwconv_ln<<<NPIX, 256, 0, stream>>>(buf1, w_dw, ln_g, ln_b, q_bias, v_bias,
                                        buf2);
    // 4. halo window attention -> (B,H,W,C) in buf1
    attn_kernel<<<NWIN * NHEADS, 64, 0, stream>>>(buf2, btab, logit_scale, buf1);
    // 5. out = attn_out @ w_proj  (32768x256 @ 256x256)
    gemm_f32<<<dim3(CC / 64, NPIX / 64), 256, 0, stream>>>(buf1, w_proj, out,
                                                           NPIX, CC, CC);
}

// Round 2
// 566.815 us; speedup vs baseline: 1.9295x; 1.9295x over previous
//
#include <hip/hip_runtime.h>
#include <hip/hip_bf16.h>
#include <cstddef>
#include <cstdint>

// Problem constants
#define BB 2
#define HH 128
#define WW 128
#define CC 256
#define WSZ 8
#define KWIN 16
#define NHEADS 8
#define HD 32
#define C3 768
#define NPIX 32768            // B*H*W
#define NWIN 512              // B * 16 * 16

typedef short bf16x8 __attribute__((ext_vector_type(8)));
typedef float f32x4  __attribute__((ext_vector_type(4)));

__device__ inline short f2bf(float f) {
    union { float f; unsigned u; } v; v.f = f;
    unsigned r = (v.u + 0x7fffu + ((v.u >> 16) & 1u)) >> 16;
    return (short)r;
}

// ---------------------------------------------------------------------------
// CPB MLP: bias_tab[529][8] = sigmoid(relu(tab @ w1 + b1) @ w2) * 16
// ---------------------------------------------------------------------------
__global__ __launch_bounds__(64) void cpb_kernel(const float* __restrict__ w1,
                                                 const float* __restrict__ b1,
                                                 const float* __restrict__ w2,
                                                 float* __restrict__ btab) {
    const int e = blockIdx.x;          // 0..528
    const int i = e / 23, j = e % 23;
    const float inv_log8 = 1.0f / logf(8.0f);
    float c0 = (float)(i - 11) * (8.0f / 7.0f);
    float c1 = (float)(j - 11) * (8.0f / 7.0f);
    float f0 = copysignf(log1pf(fabsf(c0)) * inv_log8, c0);
    float f1 = copysignf(log1pf(fabsf(c1)) * inv_log8, c1);

    const int t = threadIdx.x;
    float acc[8] = {0.f,0.f,0.f,0.f,0.f,0.f,0.f,0.f};
    for (int kk = 0; kk < 8; kk++) {
        int k = kk * 64 + t;
        float hid = f0 * w1[k] + f1 * w1[512 + k] + b1[k];
        hid = fmaxf(hid, 0.f);
        #pragma unroll
        for (int h = 0; h < 8; h++) acc[h] += hid * w2[k * 8 + h];
    }
    #pragma unroll
    for (int h = 0; h < 8; h++) {
        #pragma unroll
        for (int off = 32; off >= 1; off >>= 1) acc[h] += __shfl_xor(acc[h], off);
    }
    if (t < 8) {
        float v = acc[t];
        btab[e * 8 + t] = 16.0f / (1.0f + expf(-v));
    }
}

// ---------------------------------------------------------------------------
// fp32 GEMM: C[M,N] = A[M,K] @ B[K,N], row-major.
// ---------------------------------------------------------------------------
__global__ __launch_bounds__(256) void gemm_f32(const float* __restrict__ A,
                                                const float* __restrict__ B,
                                                float* __restrict__ C,
                                                int M, int N, int K) {
    __shared__ float As[16][65];
    __shared__ float Bs[16][64];
    const int tid = threadIdx.x;
    const int tx = tid & 15;
    const int ty = tid >> 4;
    const int rowb = blockIdx.y * 64;
    const int colb = blockIdx.x * 64;

    float acc[4][4] = {};
    for (int k0 = 0; k0 < K; k0 += 16) {
        {
            int r = tid >> 2;
            int c = (tid & 3) * 4;
            const float4 a4 = *(const float4*)(A + (size_t)(rowb + r) * K + k0 + c);
            As[c + 0][r] = a4.x; As[c + 1][r] = a4.y;
            As[c + 2][r] = a4.z; As[c + 3][r] = a4.w;
        }
        {
            int kr = tid >> 4;
            int cc = (tid & 15) * 4;
            *(float4*)&Bs[kr][cc] =
                *(const float4*)(B + (size_t)(k0 + kr) * N + colb + cc);
        }
        __syncthreads();
        #pragma unroll
        for (int kk = 0; kk < 16; kk++) {
            float a[4], b[4];
            #pragma unroll
            for (int ii = 0; ii < 4; ii++) a[ii] = As[kk][ty * 4 + ii];
            #pragma unroll
            for (int jj = 0; jj < 4; jj++) b[jj] = Bs[kk][tx * 4 + jj];
            #pragma unroll
            for (int ii = 0; ii < 4; ii++)
                #pragma unroll
                for (int jj = 0; jj < 4; jj++)
                    acc[ii][jj] += a[ii] * b[jj];
        }
        __syncthreads();
    }
    #pragma unroll
    for (int ii = 0; ii < 4; ii++) {
        float4 o = make_float4(acc[ii][0], acc[ii][1], acc[ii][2], acc[ii][3]);
        *(float4*)(C + (size_t)(rowb + ty * 4 + ii) * N + colb + tx * 4) = o;
    }
}

// ---------------------------------------------------------------------------
// Depthwise 3x3 conv (SAME) + LayerNorm(768) + qkv bias add
// ---------------------------------------------------------------------------
__global__ __launch_bounds__(256) void dwconv_ln(const float* __restrict__ in,
                                                 const float* __restrict__ wdw,
                                                 const float* __restrict__ g,
                                                 const float* __restrict__ bt,
                                                 const float* __restrict__ qb,
                                                 const float* __restrict__ vb,
                                                 float* __restrict__ out) {
    const int pix = blockIdx.x;
    const int b = pix >> 14, y = (pix >> 7) & 127, x = pix & 127;
    const int t = threadIdx.x;

    float v[3];
    #pragma unroll
    for (int i = 0; i < 3; i++) {
        const int c = t + i * 256;
        float s = 0.f;
        #pragma unroll
        for (int dy = -1; dy <= 1; dy++) {
            int yy = y + dy;
            if (yy < 0 || yy > 127) continue;
            #pragma unroll
            for (int dx = -1; dx <= 1; dx++) {
                int xx = x + dx;
                if (xx < 0 || xx > 127) continue;
                s += in[(((size_t)b * 128 + yy) * 128 + xx) * C3 + c] *
                     wdw[((dy + 1) * 3 + (dx + 1)) * C3 + c];
            }
        }
        v[i] = s;
    }

    float ls  = v[0] + v[1] + v[2];
    float lss = v[0] * v[0] + v[1] * v[1] + v[2] * v[2];
    #pragma unroll
    for (int off = 32; off >= 1; off >>= 1) {
        ls  += __shfl_xor(ls, off);
        lss += __shfl_xor(lss, off);
    }
    __shared__ float sred[8];
    const int wave = t >> 6;
    if ((t & 63) == 0) { sred[wave * 2] = ls; sred[wave * 2 + 1] = lss; }
    __syncthreads();
    float S  = sred[0] + sred[2] + sred[4] + sred[6];
    float SS = sred[1] + sred[3] + sred[5] + sred[7];
    float mu  = S * (1.0f / 768.0f);
    float var = SS * (1.0f / 768.0f) - mu * mu;
    float rs  = rsqrtf(var + 1e-5f);

    const size_t base = (size_t)pix * C3;
    #pragma unroll
    for (int i = 0; i < 3; i++) {
        const int c = t + i * 256;
        float extra = (c < 256) ? qb[c] : ((c < 512) ? 0.f : vb[c - 512]);
        out[base + c] = (v[i] - mu) * rs * g[c] + bt[c] + extra;
    }
}

// ---------------------------------------------------------------------------
// MFMA halo window attention. Block = (window, head), 256 threads = 4 waves,
// wave w handles q rows 16w..16w+15.
//   S tile: D(16q x 16key) = mfma_16x16x32(Qfrag, Kfrag)   [K-dim = HD = 32]
//   P -> LDS (bf16, XOR-swizzled) -> A-frags for PV mfmas.
// Exact softmax via static shift M = scale + 16.
// ---------------------------------------------------------------------------
__global__ __launch_bounds__(256) void attn_mfma(const float* __restrict__ qkv,
                                                 const float* __restrict__ bias_tab,
                                                 const float* __restrict__ logit_scale,
                                                 float* __restrict__ out) {
    const int blk = blockIdx.x;
    const int h = blk & 7;
    const int wid = blk >> 3;
    const int b = wid >> 8;
    const int wy = (wid >> 4) & 15;
    const int wx = wid & 15;
    const int tid = threadIdx.x;
    const int wave = tid >> 6, lane = tid & 63;
    const int quad = lane >> 4, l15 = lane & 15;

    __shared__ short Kl[256][40];     // normalized K, bf16 bits, row-major
    __shared__ short Vt[32][264];     // V transposed [dim][key], bf16 bits
    __shared__ short Pl[4][16][256];  // per-wave P, XOR-swizzled keys
    __shared__ float btab[529];

    for (int e = tid; e < 529; e += 256) btab[e] = bias_tab[e * 8 + h];

    // ---- stage K (l2-normalized) and V (transposed), one key per thread ----
    {
        const int j = tid;                         // key 0..255
        const int kr = j >> 4, kcc = j & 15;
        const int gy = wy * 8 - 4 + kr, gx = wx * 8 - 4 + kcc;
        const bool inb = ((unsigned)gy < 128u) && ((unsigned)gx < 128u);
        const float* p = qkv +
            (((size_t)(b * 128 + (inb ? gy : 0)) * 128 + (inb ? gx : 0)) * C3) +
            256 + h * HD;
        float kreg[32];
        float s2 = 0.f;
        #pragma unroll
        for (int d4 = 0; d4 < 32; d4 += 4) {
            float4 kk = inb ? *(const float4*)(p + d4)       : make_float4(0,0,0,0);
            float4 vv = inb ? *(const float4*)(p + 256 + d4) : make_float4(0,0,0,0);
            kreg[d4+0] = kk.x; kreg[d4+1] = kk.y; kreg[d4+2] = kk.z; kreg[d4+3] = kk.w;
            s2 += kk.x*kk.x + kk.y*kk.y + kk.z*kk.z + kk.w*kk.w;
            Vt[d4+0][j] = f2bf(vv.x); Vt[d4+1][j] = f2bf(vv.y);
            Vt[d4+2][j] = f2bf(vv.z); Vt[d4+3][j] = f2bf(vv.w);
        }
        const float r = rsqrtf(fmaxf(s2, 1.55e-5f));
        #pragma unroll
        for (int d = 0; d < 32; d++) Kl[j][d] = f2bf(kreg[d] * r);
    }
    __syncthreads();

    // ---- per-wave Q A-fragment: A[m=l15][k=quad*8+j] ----
    const float lscale = __expf(fminf(logit_scale[h], 4.60517019f)); // ln(100)
    const float Mshift = lscale + 16.0f;
    {
    }
    const int qrow = wave * 16 + l15;
    const int qr = qrow >> 3, qc = qrow & 7;
    const int qy = wy * 8 + qr, qx = wx * 8 + qc;
    bf16x8 afrag;
    {
        const float* qp = qkv + (((size_t)(b * 128 + qy) * 128 + qx) * C3) + h * HD + quad * 8;
        float4 a0 = *(const float4*)qp;
        float4 a1 = *(const float4*)(qp + 4);
        float s2 = a0.x*a0.x + a0.y*a0.y + a0.z*a0.z + a0.w*a0.w
                 + a1.x*a1.x + a1.y*a1.y + a1.z*a1.z + a1.w*a1.w;
        s2 += __shfl_xor(s2, 16);
        s2 += __shfl_xor(s2, 32);
        const float rq = rsqrtf(fmaxf(s2, 1.55e-5f)) * lscale;
        afrag[0] = f2bf(a0.x*rq); afrag[1] = f2bf(a0.y*rq);
        afrag[2] = f2bf(a0.z*rq); afrag[3] = f2bf(a0.w*rq);
        afrag[4] = f2bf(a1.x*rq); afrag[5] = f2bf(a1.y*rq);
        afrag[6] = f2bf(a1.z*rq); afrag[7] = f2bf(a1.w*rq);
    }

    // ---- S = Q·K^T tiles, exp, row-sums, P -> LDS ----
    float lsum[4] = {0.f, 0.f, 0.f, 0.f};
    for (int nt = 0; nt < 16; nt++) {
        bf16x8 bfrag = *(const bf16x8*)&Kl[nt * 16 + l15][quad * 8];
        f32x4 s = {0.f, 0.f, 0.f, 0.f};
        s = __builtin_amdgcn_mfma_f32_16x16x32_bf16(afrag, bfrag, s, 0, 0, 0);
        #pragma unroll
        for (int reg = 0; reg < 4; reg++) {
            const int q  = quad * 4 + reg;            // row in wave tile
            const int gq = wave * 16 + q;
            const int rqr = gq >> 3, rqc = gq & 7;
            const float rb = btab[(rqr - nt + 15) * 23 + (rqc - l15 + 15)];
            const float pv = __expf(s[reg] + rb - Mshift);
            lsum[reg] += pv;
            Pl[wave][q][(nt * 16 + l15) ^ ((q & 12) << 2)] = f2bf(pv);
        }
    }
    #pragma unroll
    for (int reg = 0; reg < 4; reg++) {
        float v = lsum[reg];
        v += __shfl_xor(v, 1); v += __shfl_xor(v, 2);
        v += __shfl_xor(v, 4); v += __shfl_xor(v, 8);
        lsum[reg] = 1.0f / v;
    }

    // ---- O = P·V ----
    f32x4 d0 = {0.f, 0.f, 0.f, 0.f};
    f32x4 d1 = {0.f, 0.f, 0.f, 0.f};
    #pragma unroll
    for (int ch = 0; ch < 8; ch++) {
        bf16x8 pa = *(const bf16x8*)&Pl[wave][l15][(ch * 32 + quad * 8) ^ ((l15 & 12) << 2)];
        bf16x8 b0 = *(const bf16x8*)&Vt[l15][ch * 32 + quad * 8];
        bf16x8 b1 = *(const bf16x8*)&Vt[l15 + 16][ch * 32 + quad * 8];
        d0 = __builtin_amdgcn_mfma_f32_16x16x32_bf16(pa, b0, d0, 0, 0, 0);
        d1 = __builtin_amdgcn_mfma_f32_16x16x32_bf16(pa, b1, d1, 0, 0, 0);
    }

    // ---- epilogue: D rows = quad*4+reg, cols = l15 (dims) ----
    #pragma unroll
    for (int reg = 0; reg < 4; reg++) {
        const int gq = wave * 16 + quad * 4 + reg;
        const int oqr = gq >> 3, oqc = gq & 7;
        const int oy = wy * 8 + oqr, ox = wx * 8 + oqc;
        float* op = out + (((size_t)(b * 128 + oy) * 128 + ox) * CC) + h * HD;
        op[l15]      = d0[reg] * lsum[reg];
        op[16 + l15] = d1[reg] * lsum[reg];
    }
}

// ---------------------------------------------------------------------------
extern "C" void kernel_launch(void* const* d_in, const int* in_sizes, int n_in,
                              void* d_out, int out_size, void* d_ws, size_t ws_size,
                              hipStream_t stream) {
    const float* x           = (const float*)d_in[0];
    const float* w_qkv       = (const float*)d_in[1];
    const float* w_dw        = (const float*)d_in[2];
    const float* ln_g        = (const float*)d_in[3];
    const float* ln_b        = (const float*)d_in[4];
    const float* q_bias      = (const float*)d_in[5];
    const float* v_bias      = (const float*)d_in[6];
    const float* logit_scale = (const float*)d_in[7];
    const float* cpb_w1      = (const float*)d_in[8];
    const float* cpb_b1      = (const float*)d_in[9];
    const float* cpb_w2      = (const float*)d_in[10];
    const float* w_proj      = (const float*)d_in[11];
    float* out = (float*)d_out;

    char* ws = (char*)d_ws;
    const size_t BUF_BYTES = (size_t)NPIX * C3 * sizeof(float);   // 96 MB
    float* buf1 = (float*)ws;                       // qkv0, later attn out
    float* buf2 = (float*)(ws + BUF_BYTES);         // qkv post conv+LN
    float* btab = (float*)(ws + 2 * BUF_BYTES);     // 529*8 bias table

    cpb_kernel<<<529, 64, 0, stream>>>(cpb_w1, cpb_b1, cpb_w2, btab);
    gemm_f32<<<dim3(C3 / 64, NPIX / 64), 256, 0, stream>>>(x, w_qkv, buf1,
                                                           NPIX, C3, CC);
    dwconv_ln<<<NPIX, 256, 0, stream>>>(buf1, w_dw, ln_g, ln_b, q_bias, v_bias,
                                        buf2);
    attn_mfma<<<NWIN * NHEADS, 256, 0, stream>>>(buf2, btab, logit_scale, buf1);
    gemm_f32<<<dim3(CC / 64, NPIX / 64), 256, 0, stream>>>(buf1, w_proj, out,
                                                           NPIX, CC, CC);
}

// Round 3
// 364.186 us; speedup vs baseline: 3.0030x; 1.5564x over previous
//
#include <hip/hip_runtime.h>
#include <hip/hip_bf16.h>
#include <hip/hip_fp16.h>
#include <cstddef>
#include <cstdint>

// Problem constants
#define BB 2
#define HH 128
#define WW 128
#define CC 256
#define WSZ 8
#define KWIN 16
#define NHEADS 8
#define HD 32
#define C3 768
#define NPIX 32768            // B*H*W
#define NWIN 512              // B * 16 * 16

typedef short    bf16x8 __attribute__((ext_vector_type(8)));
typedef _Float16 half8  __attribute__((ext_vector_type(8)));
typedef _Float16 half4v __attribute__((ext_vector_type(4)));
typedef float    f32x4  __attribute__((ext_vector_type(4)));

__device__ inline short f2bf(float f) {
    union { float f; unsigned u; } v; v.f = f;
    unsigned r = (v.u + 0x7fffu + ((v.u >> 16) & 1u)) >> 16;
    return (short)r;
}

__device__ inline void gload_lds16(const _Float16* g, _Float16* l) {
    __builtin_amdgcn_global_load_lds(
        (const __attribute__((address_space(1))) unsigned int*)g,
        (__attribute__((address_space(3))) unsigned int*)l, 16, 0, 0);
}

// ---------------------------------------------------------------------------
// CPB MLP: bias_tab[529][8] = sigmoid(relu(tab @ w1 + b1) @ w2) * 16
// ---------------------------------------------------------------------------
__global__ __launch_bounds__(64) void cpb_kernel(const float* __restrict__ w1,
                                                 const float* __restrict__ b1,
                                                 const float* __restrict__ w2,
                                                 float* __restrict__ btab) {
    const int e = blockIdx.x;          // 0..528
    const int i = e / 23, j = e % 23;
    const float inv_log8 = 1.0f / logf(8.0f);
    float c0 = (float)(i - 11) * (8.0f / 7.0f);
    float c1 = (float)(j - 11) * (8.0f / 7.0f);
    float f0 = copysignf(log1pf(fabsf(c0)) * inv_log8, c0);
    float f1 = copysignf(log1pf(fabsf(c1)) * inv_log8, c1);

    const int t = threadIdx.x;
    float acc[8] = {0.f,0.f,0.f,0.f,0.f,0.f,0.f,0.f};
    for (int kk = 0; kk < 8; kk++) {
        int k = kk * 64 + t;
        float hid = f0 * w1[k] + f1 * w1[512 + k] + b1[k];
        hid = fmaxf(hid, 0.f);
        #pragma unroll
        for (int h = 0; h < 8; h++) acc[h] += hid * w2[k * 8 + h];
    }
    #pragma unroll
    for (int h = 0; h < 8; h++) {
        #pragma unroll
        for (int off = 32; off >= 1; off >>= 1) acc[h] += __shfl_xor(acc[h], off);
    }
    if (t < 8) {
        float v = acc[t];
        btab[e * 8 + t] = 16.0f / (1.0f + expf(-v));
    }
}

// ---------------------------------------------------------------------------
// fp32 -> fp16 elementwise convert (4 elems/thread)
// ---------------------------------------------------------------------------
__global__ __launch_bounds__(256) void cvt_f32_f16(const float* __restrict__ src,
                                                   _Float16* __restrict__ dst,
                                                   int n4) {
    int i = blockIdx.x * 256 + threadIdx.x;
    if (i >= n4) return;
    float4 v = *(const float4*)(src + (size_t)i * 4);
    half4v o; o[0] = (_Float16)v.x; o[1] = (_Float16)v.y;
    o[2] = (_Float16)v.z; o[3] = (_Float16)v.w;
    *(half4v*)(dst + (size_t)i * 4) = o;
}

// ---------------------------------------------------------------------------
// transpose + convert: src fp32 [R][Cn] -> dst fp16 [Cn][R].  32x32 LDS tile.
// grid (Cn/32, R/32), 256 threads (32x8)
// ---------------------------------------------------------------------------
__global__ __launch_bounds__(256) void transpose_cvt(const float* __restrict__ src,
                                                     _Float16* __restrict__ dst,
                                                     int R, int Cn) {
    __shared__ float t[32][33];
    const int bx = blockIdx.x, by = blockIdx.y;
    const int tx = threadIdx.x & 31, ty = threadIdx.x >> 5;
    #pragma unroll
    for (int i = 0; i < 4; i++) {
        int r = by * 32 + ty + i * 8;
        t[ty + i * 8][tx] = src[(size_t)r * Cn + bx * 32 + tx];
    }
    __syncthreads();
    #pragma unroll
    for (int i = 0; i < 4; i++) {
        int dr = bx * 32 + ty + i * 8;          // orig col
        dst[(size_t)dr * R + by * 32 + tx] = (_Float16)t[tx][ty + i * 8];
    }
}

// ---------------------------------------------------------------------------
// fp16 MFMA NT-GEMM:  C[M][N] = A[M][K] * Bt[N][K]^T, fp32 accumulate.
// 128x128 tile, BK=64, 256 threads (4 waves, 2x2 of 64x64).
// global_load_lds width-16 staging; XOR-swizzled k-groups (phys = g ^ (m&7))
// keep staging contiguous AND frag ds_read_b128 at 2-way conflicts (free).
// ---------------------------------------------------------------------------
template <typename OT>
__global__ __launch_bounds__(256) void gemm_f16(const _Float16* __restrict__ A,
                                                const _Float16* __restrict__ Bt,
                                                OT* __restrict__ C,
                                                int M, int N, int K) {
    __shared__ _Float16 Ash[128][64];
    __shared__ _Float16 Bsh[128][64];
    const int tid = threadIdx.x;
    const int wv = tid >> 6, ln = tid & 63;
    const int quad = ln >> 4, l15 = ln & 15;
    const int rowb = blockIdx.y * 128;
    const int colb = blockIdx.x * 128;
    const int wm = (wv >> 1) * 64, wn = (wv & 1) * 64;

    const int r8 = ln >> 3, g = ln & 7;
    const int kg = g ^ r8;                    // swizzled logical k-group

    f32x4 acc[4][4] = {};
    for (int k0 = 0; k0 < K; k0 += 64) {
        // ---- stage A and Bt tiles (8 rows / wave-inst) ----
        #pragma unroll
        for (int i = 0; i < 4; i++) {
            const int m = wv * 32 + i * 8 + r8;
            gload_lds16(A + (size_t)(rowb + m) * K + k0 + kg * 8,
                        &Ash[wv * 32 + i * 8][0]);
            gload_lds16(Bt + (size_t)(colb + m) * K + k0 + kg * 8,
                        &Bsh[wv * 32 + i * 8][0]);
        }
        __syncthreads();
        #pragma unroll
        for (int kk = 0; kk < 2; kk++) {
            const int phys = ((kk * 4 + quad) ^ (l15 & 7)) * 8;
            half8 a[4], b[4];
            #pragma unroll
            for (int i = 0; i < 4; i++)
                a[i] = *(const half8*)&Ash[wm + i * 16 + l15][phys];
            #pragma unroll
            for (int j = 0; j < 4; j++)
                b[j] = *(const half8*)&Bsh[wn + j * 16 + l15][phys];
            #pragma unroll
            for (int i = 0; i < 4; i++)
                #pragma unroll
                for (int j = 0; j < 4; j++)
                    acc[i][j] = __builtin_amdgcn_mfma_f32_16x16x32_f16(
                        a[i], b[j], acc[i][j], 0, 0, 0);
        }
        __syncthreads();
    }
    // ---- epilogue: D row = quad*4+reg, col = l15 ----
    #pragma unroll
    for (int i = 0; i < 4; i++) {
        #pragma unroll
        for (int reg = 0; reg < 4; reg++) {
            const size_t row = rowb + wm + i * 16 + quad * 4 + reg;
            #pragma unroll
            for (int j = 0; j < 4; j++) {
                C[row * N + colb + wn + j * 16 + l15] = (OT)acc[i][j][reg];
            }
        }
    }
}

// ---------------------------------------------------------------------------
// Depthwise 3x3 conv (SAME) + LayerNorm(768) + qkv bias add.  fp16 in/out.
// ---------------------------------------------------------------------------
__global__ __launch_bounds__(256) void dwconv_ln(const _Float16* __restrict__ in,
                                                 const float* __restrict__ wdw,
                                                 const float* __restrict__ g,
                                                 const float* __restrict__ bt,
                                                 const float* __restrict__ qb,
                                                 const float* __restrict__ vb,
                                                 _Float16* __restrict__ out) {
    const int pix = blockIdx.x;
    const int b = pix >> 14, y = (pix >> 7) & 127, x = pix & 127;
    const int t = threadIdx.x;

    float v[3];
    #pragma unroll
    for (int i = 0; i < 3; i++) {
        const int c = t + i * 256;
        float s = 0.f;
        #pragma unroll
        for (int dy = -1; dy <= 1; dy++) {
            int yy = y + dy;
            if (yy < 0 || yy > 127) continue;
            #pragma unroll
            for (int dx = -1; dx <= 1; dx++) {
                int xx = x + dx;
                if (xx < 0 || xx > 127) continue;
                s += (float)in[(((size_t)b * 128 + yy) * 128 + xx) * C3 + c] *
                     wdw[((dy + 1) * 3 + (dx + 1)) * C3 + c];
            }
        }
        v[i] = s;
    }

    float ls  = v[0] + v[1] + v[2];
    float lss = v[0] * v[0] + v[1] * v[1] + v[2] * v[2];
    #pragma unroll
    for (int off = 32; off >= 1; off >>= 1) {
        ls  += __shfl_xor(ls, off);
        lss += __shfl_xor(lss, off);
    }
    __shared__ float sred[8];
    const int wave = t >> 6;
    if ((t & 63) == 0) { sred[wave * 2] = ls; sred[wave * 2 + 1] = lss; }
    __syncthreads();
    float S  = sred[0] + sred[2] + sred[4] + sred[6];
    float SS = sred[1] + sred[3] + sred[5] + sred[7];
    float mu  = S * (1.0f / 768.0f);
    float var = SS * (1.0f / 768.0f) - mu * mu;
    float rs  = rsqrtf(var + 1e-5f);

    const size_t base = (size_t)pix * C3;
    #pragma unroll
    for (int i = 0; i < 3; i++) {
        const int c = t + i * 256;
        float extra = (c < 256) ? qb[c] : ((c < 512) ? 0.f : vb[c - 512]);
        out[base + c] = (_Float16)((v[i] - mu) * rs * g[c] + bt[c] + extra);
    }
}

// ---------------------------------------------------------------------------
// MFMA halo window attention (fp16 in/out, bf16 MFMA internals).
// Block = (window, head), 256 threads = 4 waves, wave w -> q rows 16w..16w+15.
// Exact softmax via static shift M = scale + 16 (bf16 P: exponent range safe).
// ---------------------------------------------------------------------------
__global__ __launch_bounds__(256) void attn_mfma(const _Float16* __restrict__ qkv,
                                                 const float* __restrict__ bias_tab,
                                                 const float* __restrict__ logit_scale,
                                                 _Float16* __restrict__ out) {
    const int blk = blockIdx.x;
    const int h = blk & 7;
    const int wid = blk >> 3;
    const int b = wid >> 8;
    const int wy = (wid >> 4) & 15;
    const int wx = wid & 15;
    const int tid = threadIdx.x;
    const int wave = tid >> 6, lane = tid & 63;
    const int quad = lane >> 4, l15 = lane & 15;

    __shared__ short Kl[256][40];     // normalized K, bf16 bits, row-major
    __shared__ short Vt[32][264];     // V transposed [dim][key], bf16 bits
    __shared__ short Pl[4][16][256];  // per-wave P, XOR-swizzled keys
    __shared__ float btab[529];

    for (int e = tid; e < 529; e += 256) btab[e] = bias_tab[e * 8 + h];

    // ---- stage K (l2-normalized) and V (transposed), one key per thread ----
    {
        const int j = tid;                         // key 0..255
        const int kr = j >> 4, kcc = j & 15;
        const int gy = wy * 8 - 4 + kr, gx = wx * 8 - 4 + kcc;
        const bool inb = ((unsigned)gy < 128u) && ((unsigned)gx < 128u);
        const _Float16* p = qkv +
            (((size_t)(b * 128 + (inb ? gy : 0)) * 128 + (inb ? gx : 0)) * C3) +
            256 + h * HD;
        float kreg[32];
        float s2 = 0.f;
        #pragma unroll
        for (int d8 = 0; d8 < 32; d8 += 8) {
            half8 kk, vv;
            if (inb) { kk = *(const half8*)(p + d8); vv = *(const half8*)(p + 256 + d8); }
            else     { kk = (half8)(_Float16)0;      vv = (half8)(_Float16)0; }
            #pragma unroll
            for (int u = 0; u < 8; u++) {
                float kf = (float)kk[u];
                kreg[d8 + u] = kf;
                s2 += kf * kf;
                Vt[d8 + u][j] = f2bf((float)vv[u]);
            }
        }
        const float r = rsqrtf(fmaxf(s2, 1.55e-5f));
        #pragma unroll
        for (int d = 0; d < 32; d++) Kl[j][d] = f2bf(kreg[d] * r);
    }
    __syncthreads();

    // ---- per-wave Q A-fragment: A[m=l15][k=quad*8+j] ----
    const float lscale = __expf(fminf(logit_scale[h], 4.60517019f)); // ln(100)
    const float Mshift = lscale + 16.0f;
    const int qrow = wave * 16 + l15;
    const int qr = qrow >> 3, qc = qrow & 7;
    const int qy = wy * 8 + qr, qx = wx * 8 + qc;
    bf16x8 afrag;
    {
        const _Float16* qp = qkv + (((size_t)(b * 128 + qy) * 128 + qx) * C3) + h * HD + quad * 8;
        half8 q8 = *(const half8*)qp;
        float qf[8];
        float s2 = 0.f;
        #pragma unroll
        for (int u = 0; u < 8; u++) { qf[u] = (float)q8[u]; s2 += qf[u] * qf[u]; }
        s2 += __shfl_xor(s2, 16);
        s2 += __shfl_xor(s2, 32);
        const float rq = rsqrtf(fmaxf(s2, 1.55e-5f)) * lscale;
        #pragma unroll
        for (int u = 0; u < 8; u++) afrag[u] = f2bf(qf[u] * rq);
    }

    // ---- S = Q.K^T tiles, exp, row-sums, P -> LDS ----
    float lsum[4] = {0.f, 0.f, 0.f, 0.f};
    for (int nt = 0; nt < 16; nt++) {
        bf16x8 bfrag = *(const bf16x8*)&Kl[nt * 16 + l15][quad * 8];
        f32x4 s = {0.f, 0.f, 0.f, 0.f};
        s = __builtin_amdgcn_mfma_f32_16x16x32_bf16(afrag, bfrag, s, 0, 0, 0);
        #pragma unroll
        for (int reg = 0; reg < 4; reg++) {
            const int q  = quad * 4 + reg;            // row in wave tile
            const int gq = wave * 16 + q;
            const int rqr = gq >> 3, rqc = gq & 7;
            const float rb = btab[(rqr - nt + 15) * 23 + (rqc - l15 + 15)];
            const float pv = __expf(s[reg] + rb - Mshift);
            lsum[reg] += pv;
            Pl[wave][q][(nt * 16 + l15) ^ ((q & 12) << 2)] = f2bf(pv);
        }
    }
    #pragma unroll
    for (int reg = 0; reg < 4; reg++) {
        float v = lsum[reg];
        v += __shfl_xor(v, 1); v += __shfl_xor(v, 2);
        v += __shfl_xor(v, 4); v += __shfl_xor(v, 8);
        lsum[reg] = 1.0f / v;
    }

    // ---- O = P.V ----
    f32x4 d0 = {0.f, 0.f, 0.f, 0.f};
    f32x4 d1 = {0.f, 0.f, 0.f, 0.f};
    #pragma unroll
    for (int ch = 0; ch < 8; ch++) {
        bf16x8 pa = *(const bf16x8*)&Pl[wave][l15][(ch * 32 + quad * 8) ^ ((l15 & 12) << 2)];
        bf16x8 b0 = *(const bf16x8*)&Vt[l15][ch * 32 + quad * 8];
        bf16x8 b1 = *(const bf16x8*)&Vt[l15 + 16][ch * 32 + quad * 8];
        d0 = __builtin_amdgcn_mfma_f32_16x16x32_bf16(pa, b0, d0, 0, 0, 0);
        d1 = __builtin_amdgcn_mfma_f32_16x16x32_bf16(pa, b1, d1, 0, 0, 0);
    }

    // ---- epilogue ----
    #pragma unroll
    for (int reg = 0; reg < 4; reg++) {
        const int gq = wave * 16 + quad * 4 + reg;
        const int oqr = gq >> 3, oqc = gq & 7;
        const int oy = wy * 8 + oqr, ox = wx * 8 + oqc;
        _Float16* op = out + (((size_t)(b * 128 + oy) * 128 + ox) * CC) + h * HD;
        op[l15]      = (_Float16)(d0[reg] * lsum[reg]);
        op[16 + l15] = (_Float16)(d1[reg] * lsum[reg]);
    }
}

// ---------------------------------------------------------------------------
extern "C" void kernel_launch(void* const* d_in, const int* in_sizes, int n_in,
                              void* d_out, int out_size, void* d_ws, size_t ws_size,
                              hipStream_t stream) {
    const float* x           = (const float*)d_in[0];
    const float* w_qkv       = (const float*)d_in[1];
    const float* w_dw        = (const float*)d_in[2];
    const float* ln_g        = (const float*)d_in[3];
    const float* ln_b        = (const float*)d_in[4];
    const float* q_bias      = (const float*)d_in[5];
    const float* v_bias      = (const float*)d_in[6];
    const float* logit_scale = (const float*)d_in[7];
    const float* cpb_w1      = (const float*)d_in[8];
    const float* cpb_b1      = (const float*)d_in[9];
    const float* cpb_w2      = (const float*)d_in[10];
    const float* w_proj      = (const float*)d_in[11];
    float* out = (float*)d_out;

    char* ws = (char*)d_ws;
    _Float16* xh     = (_Float16*)(ws);                          // 16.78 MB
    _Float16* qkv0h  = (_Float16*)(ws + 16777216);               // 50.33 MB
    _Float16* qkvh   = (_Float16*)(ws + 67108864);               // 50.33 MB
    _Float16* attnh  = (_Float16*)(ws + 117440512);              // 16.78 MB
    _Float16* wqkvT  = (_Float16*)(ws + 134217728);              // 0.39 MB
    _Float16* wprojT = (_Float16*)(ws + 134610944);              // 0.13 MB
    float*    btab   = (float*)   (ws + 134742016);              // 17 KB

    cpb_kernel<<<529, 64, 0, stream>>>(cpb_w1, cpb_b1, cpb_w2, btab);
    cvt_f32_f16<<<(NPIX * CC / 4 + 255) / 256, 256, 0, stream>>>(x, xh, NPIX * CC / 4);
    transpose_cvt<<<dim3(C3 / 32, CC / 32), 256, 0, stream>>>(w_qkv, wqkvT, CC, C3);
    transpose_cvt<<<dim3(CC / 32, CC / 32), 256, 0, stream>>>(w_proj, wprojT, CC, CC);

    // qkv0 = x @ w_qkv    (fp16 MFMA, fp16 out)
    gemm_f16<_Float16><<<dim3(C3 / 128, NPIX / 128), 256, 0, stream>>>(
        xh, wqkvT, qkv0h, NPIX, C3, CC);
    // depthwise 3x3 + LN + bias
    dwconv_ln<<<NPIX, 256, 0, stream>>>(qkv0h, w_dw, ln_g, ln_b, q_bias, v_bias,
                                        qkvh);
    // halo window attention
    attn_mfma<<<NWIN * NHEADS, 256, 0, stream>>>(qkvh, btab, logit_scale, attnh);
    // out = attn_out @ w_proj   (fp32 out)
    gemm_f16<float><<<dim3(CC / 128, NPIX / 128), 256, 0, stream>>>(
        attnh, wprojT, out, NPIX, CC, CC);
}

// Round 4
// 292.992 us; speedup vs baseline: 3.7327x; 1.2430x over previous
//
#include <hip/hip_runtime.h>
#include <hip/hip_bf16.h>
#include <hip/hip_fp16.h>
#include <cstddef>
#include <cstdint>

// Problem constants
#define BB 2
#define HH 128
#define WW 128
#define CC 256
#define WSZ 8
#define KWIN 16
#define NHEADS 8
#define HD 32
#define C3 768
#define NPIX 32768            // B*H*W
#define NWIN 512              // B * 16 * 16

typedef short    bf16x8 __attribute__((ext_vector_type(8)));
typedef _Float16 half8  __attribute__((ext_vector_type(8)));
typedef _Float16 half4v __attribute__((ext_vector_type(4)));
typedef float    f32x4  __attribute__((ext_vector_type(4)));

__device__ inline short f2bf(float f) {
    union { float f; unsigned u; } v; v.f = f;
    unsigned r = (v.u + 0x7fffu + ((v.u >> 16) & 1u)) >> 16;
    return (short)r;
}

__device__ inline void gload_lds16(const _Float16* g, _Float16* l) {
    __builtin_amdgcn_global_load_lds(
        (const __attribute__((address_space(1))) unsigned int*)g,
        (__attribute__((address_space(3))) unsigned int*)l, 16, 0, 0);
}

// ---------------------------------------------------------------------------
// CPB MLP: bias_tab[529][8] = sigmoid(relu(tab @ w1 + b1) @ w2) * 16
// ---------------------------------------------------------------------------
__global__ __launch_bounds__(64) void cpb_kernel(const float* __restrict__ w1,
                                                 const float* __restrict__ b1,
                                                 const float* __restrict__ w2,
                                                 float* __restrict__ btab) {
    const int e = blockIdx.x;          // 0..528
    const int i = e / 23, j = e % 23;
    const float inv_log8 = 1.0f / logf(8.0f);
    float c0 = (float)(i - 11) * (8.0f / 7.0f);
    float c1 = (float)(j - 11) * (8.0f / 7.0f);
    float f0 = copysignf(log1pf(fabsf(c0)) * inv_log8, c0);
    float f1 = copysignf(log1pf(fabsf(c1)) * inv_log8, c1);

    const int t = threadIdx.x;
    float acc[8] = {0.f,0.f,0.f,0.f,0.f,0.f,0.f,0.f};
    for (int kk = 0; kk < 8; kk++) {
        int k = kk * 64 + t;
        float hid = f0 * w1[k] + f1 * w1[512 + k] + b1[k];
        hid = fmaxf(hid, 0.f);
        #pragma unroll
        for (int h = 0; h < 8; h++) acc[h] += hid * w2[k * 8 + h];
    }
    #pragma unroll
    for (int h = 0; h < 8; h++) {
        #pragma unroll
        for (int off = 32; off >= 1; off >>= 1) acc[h] += __shfl_xor(acc[h], off);
    }
    if (t < 8) {
        float v = acc[t];
        btab[e * 8 + t] = 16.0f / (1.0f + expf(-v));
    }
}

// ---------------------------------------------------------------------------
// fp32 -> fp16 elementwise convert (4 elems/thread)
// ---------------------------------------------------------------------------
__global__ __launch_bounds__(256) void cvt_f32_f16(const float* __restrict__ src,
                                                   _Float16* __restrict__ dst,
                                                   int n4) {
    int i = blockIdx.x * 256 + threadIdx.x;
    if (i >= n4) return;
    float4 v = *(const float4*)(src + (size_t)i * 4);
    half4v o; o[0] = (_Float16)v.x; o[1] = (_Float16)v.y;
    o[2] = (_Float16)v.z; o[3] = (_Float16)v.w;
    *(half4v*)(dst + (size_t)i * 4) = o;
}

// ---------------------------------------------------------------------------
// transpose + convert: src fp32 [R][Cn] -> dst fp16 [Cn][R].  32x32 LDS tile.
// ---------------------------------------------------------------------------
__global__ __launch_bounds__(256) void transpose_cvt(const float* __restrict__ src,
                                                     _Float16* __restrict__ dst,
                                                     int R, int Cn) {
    __shared__ float t[32][33];
    const int bx = blockIdx.x, by = blockIdx.y;
    const int tx = threadIdx.x & 31, ty = threadIdx.x >> 5;
    #pragma unroll
    for (int i = 0; i < 4; i++) {
        int r = by * 32 + ty + i * 8;
        t[ty + i * 8][tx] = src[(size_t)r * Cn + bx * 32 + tx];
    }
    __syncthreads();
    #pragma unroll
    for (int i = 0; i < 4; i++) {
        int dr = bx * 32 + ty + i * 8;          // orig col
        dst[(size_t)dr * R + by * 32 + tx] = (_Float16)t[tx][ty + i * 8];
    }
}

// ---------------------------------------------------------------------------
// fp16 MFMA NT-GEMM:  C[M][N] = A[M][K] * Bt[N][K]^T, fp32 accumulate.
// 128x128 tile, BK=64, 256 threads (4 waves, 2x2 of 64x64).
// ---------------------------------------------------------------------------
template <typename OT>
__global__ __launch_bounds__(256) void gemm_f16(const _Float16* __restrict__ A,
                                                const _Float16* __restrict__ Bt,
                                                OT* __restrict__ C,
                                                int M, int N, int K) {
    __shared__ _Float16 Ash[128][64];
    __shared__ _Float16 Bsh[128][64];
    const int tid = threadIdx.x;
    const int wv = tid >> 6, ln = tid & 63;
    const int quad = ln >> 4, l15 = ln & 15;
    const int rowb = blockIdx.y * 128;
    const int colb = blockIdx.x * 128;
    const int wm = (wv >> 1) * 64, wn = (wv & 1) * 64;

    const int r8 = ln >> 3, g = ln & 7;
    const int kg = g ^ r8;                    // swizzled logical k-group

    f32x4 acc[4][4] = {};
    for (int k0 = 0; k0 < K; k0 += 64) {
        #pragma unroll
        for (int i = 0; i < 4; i++) {
            const int m = wv * 32 + i * 8 + r8;
            gload_lds16(A + (size_t)(rowb + m) * K + k0 + kg * 8,
                        &Ash[wv * 32 + i * 8][0]);
            gload_lds16(Bt + (size_t)(colb + m) * K + k0 + kg * 8,
                        &Bsh[wv * 32 + i * 8][0]);
        }
        __syncthreads();
        #pragma unroll
        for (int kk = 0; kk < 2; kk++) {
            const int phys = ((kk * 4 + quad) ^ (l15 & 7)) * 8;
            half8 a[4], b[4];
            #pragma unroll
            for (int i = 0; i < 4; i++)
                a[i] = *(const half8*)&Ash[wm + i * 16 + l15][phys];
            #pragma unroll
            for (int j = 0; j < 4; j++)
                b[j] = *(const half8*)&Bsh[wn + j * 16 + l15][phys];
            #pragma unroll
            for (int i = 0; i < 4; i++)
                #pragma unroll
                for (int j = 0; j < 4; j++)
                    acc[i][j] = __builtin_amdgcn_mfma_f32_16x16x32_f16(
                        a[i], b[j], acc[i][j], 0, 0, 0);
        }
        __syncthreads();
    }
    #pragma unroll
    for (int i = 0; i < 4; i++) {
        #pragma unroll
        for (int reg = 0; reg < 4; reg++) {
            const size_t row = rowb + wm + i * 16 + quad * 4 + reg;
            #pragma unroll
            for (int j = 0; j < 4; j++) {
                C[row * N + colb + wn + j * 16 + l15] = (OT)acc[i][j][reg];
            }
        }
    }
}

// ---------------------------------------------------------------------------
// Depthwise 3x3 conv (SAME) + LayerNorm(768) + qkv bias add.  fp16 in/out.
// v2: 192 threads = 1 pixel, 4 channels/thread.  half4 input taps, weights
// hoisted to registers (9 x float4).  18 VMEM inst/thread vs v1's 54.
// ---------------------------------------------------------------------------
__global__ __launch_bounds__(192) void dwconv_ln(const _Float16* __restrict__ in,
                                                 const float* __restrict__ wdw,
                                                 const float* __restrict__ g,
                                                 const float* __restrict__ bt,
                                                 const float* __restrict__ qb,
                                                 const float* __restrict__ vb,
                                                 _Float16* __restrict__ out) {
    const int pix = blockIdx.x;
    const int b = pix >> 14, y = (pix >> 7) & 127, x = pix & 127;
    const int t = threadIdx.x;        // 0..191
    const int c0 = t * 4;             // channel base

    // hoist weights for this thread's 4 channels (L1-resident 27KB table)
    float4 w[9];
    #pragma unroll
    for (int tap = 0; tap < 9; tap++)
        w[tap] = *(const float4*)(wdw + tap * C3 + c0);

    float acc0 = 0.f, acc1 = 0.f, acc2 = 0.f, acc3 = 0.f;
    #pragma unroll
    for (int dy = -1; dy <= 1; dy++) {
        const int yy = y + dy;
        const bool yok = (unsigned)yy < 128u;
        #pragma unroll
        for (int dx = -1; dx <= 1; dx++) {
            const int xx = x + dx;
            if (yok && (unsigned)xx < 128u) {
                const half4v v4 = *(const half4v*)(in +
                    (((size_t)(b * 128 + yy) * 128 + xx) * C3) + c0);
                const int tap = (dy + 1) * 3 + (dx + 1);
                acc0 += (float)v4[0] * w[tap].x;
                acc1 += (float)v4[1] * w[tap].y;
                acc2 += (float)v4[2] * w[tap].z;
                acc3 += (float)v4[3] * w[tap].w;
            }
        }
    }

    float ls  = acc0 + acc1 + acc2 + acc3;
    float lss = acc0 * acc0 + acc1 * acc1 + acc2 * acc2 + acc3 * acc3;
    #pragma unroll
    for (int off = 32; off >= 1; off >>= 1) {
        ls  += __shfl_xor(ls, off);
        lss += __shfl_xor(lss, off);
    }
    __shared__ float sred[6];
    const int wave = t >> 6;
    if ((t & 63) == 0) { sred[wave * 2] = ls; sred[wave * 2 + 1] = lss; }
    __syncthreads();
    const float S  = sred[0] + sred[2] + sred[4];
    const float SS = sred[1] + sred[3] + sred[5];
    const float mu  = S * (1.0f / 768.0f);
    const float var = SS * (1.0f / 768.0f) - mu * mu;
    const float rs  = rsqrtf(var + 1e-5f);

    // gamma/beta + q/v bias for the 4 channels
    const float4 g4 = *(const float4*)(g + c0);
    const float4 b4 = *(const float4*)(bt + c0);
    float e0 = 0.f, e1 = 0.f, e2 = 0.f, e3 = 0.f;
    if (c0 < 256) {
        const float4 q4 = *(const float4*)(qb + c0);
        e0 = q4.x; e1 = q4.y; e2 = q4.z; e3 = q4.w;
    } else if (c0 >= 512) {
        const float4 v4 = *(const float4*)(vb + c0 - 512);
        e0 = v4.x; e1 = v4.y; e2 = v4.z; e3 = v4.w;
    }

    half4v o;
    o[0] = (_Float16)((acc0 - mu) * rs * g4.x + b4.x + e0);
    o[1] = (_Float16)((acc1 - mu) * rs * g4.y + b4.y + e1);
    o[2] = (_Float16)((acc2 - mu) * rs * g4.z + b4.z + e2);
    o[3] = (_Float16)((acc3 - mu) * rs * g4.w + b4.w + e3);
    *(half4v*)(out + (size_t)pix * C3 + c0) = o;
}

// ---------------------------------------------------------------------------
// MFMA halo window attention (fp16 in/out, bf16 MFMA internals).
// ---------------------------------------------------------------------------
__global__ __launch_bounds__(256) void attn_mfma(const _Float16* __restrict__ qkv,
                                                 const float* __restrict__ bias_tab,
                                                 const float* __restrict__ logit_scale,
                                                 _Float16* __restrict__ out) {
    const int blk = blockIdx.x;
    const int h = blk & 7;
    const int wid = blk >> 3;
    const int b = wid >> 8;
    const int wy = (wid >> 4) & 15;
    const int wx = wid & 15;
    const int tid = threadIdx.x;
    const int wave = tid >> 6, lane = tid & 63;
    const int quad = lane >> 4, l15 = lane & 15;

    __shared__ short Kl[256][40];     // normalized K, bf16 bits, row-major
    __shared__ short Vt[32][264];     // V transposed [dim][key], bf16 bits
    __shared__ short Pl[4][16][256];  // per-wave P, XOR-swizzled keys
    __shared__ float btab[529];

    for (int e = tid; e < 529; e += 256) btab[e] = bias_tab[e * 8 + h];

    // ---- stage K (l2-normalized) and V (transposed), one key per thread ----
    {
        const int j = tid;                         // key 0..255
        const int kr = j >> 4, kcc = j & 15;
        const int gy = wy * 8 - 4 + kr, gx = wx * 8 - 4 + kcc;
        const bool inb = ((unsigned)gy < 128u) && ((unsigned)gx < 128u);
        const _Float16* p = qkv +
            (((size_t)(b * 128 + (inb ? gy : 0)) * 128 + (inb ? gx : 0)) * C3) +
            256 + h * HD;
        float kreg[32];
        float s2 = 0.f;
        #pragma unroll
        for (int d8 = 0; d8 < 32; d8 += 8) {
            half8 kk, vv;
            if (inb) { kk = *(const half8*)(p + d8); vv = *(const half8*)(p + 256 + d8); }
            else     { kk = (half8)(_Float16)0;      vv = (half8)(_Float16)0; }
            #pragma unroll
            for (int u = 0; u < 8; u++) {
                float kf = (float)kk[u];
                kreg[d8 + u] = kf;
                s2 += kf * kf;
                Vt[d8 + u][j] = f2bf((float)vv[u]);
            }
        }
        const float r = rsqrtf(fmaxf(s2, 1.55e-5f));
        #pragma unroll
        for (int d = 0; d < 32; d++) Kl[j][d] = f2bf(kreg[d] * r);
    }
    __syncthreads();

    // ---- per-wave Q A-fragment: A[m=l15][k=quad*8+j] ----
    const float lscale = __expf(fminf(logit_scale[h], 4.60517019f)); // ln(100)
    const float Mshift = lscale + 16.0f;
    const int qrow = wave * 16 + l15;
    const int qr = qrow >> 3, qc = qrow & 7;
    const int qy = wy * 8 + qr, qx = wx * 8 + qc;
    bf16x8 afrag;
    {
        const _Float16* qp = qkv + (((size_t)(b * 128 + qy) * 128 + qx) * C3) + h * HD + quad * 8;
        half8 q8 = *(const half8*)qp;
        float qf[8];
        float s2 = 0.f;
        #pragma unroll
        for (int u = 0; u < 8; u++) { qf[u] = (float)q8[u]; s2 += qf[u] * qf[u]; }
        s2 += __shfl_xor(s2, 16);
        s2 += __shfl_xor(s2, 32);
        const float rq = rsqrtf(fmaxf(s2, 1.55e-5f)) * lscale;
        #pragma unroll
        for (int u = 0; u < 8; u++) afrag[u] = f2bf(qf[u] * rq);
    }

    // ---- S = Q.K^T tiles, exp, row-sums, P -> LDS ----
    float lsum[4] = {0.f, 0.f, 0.f, 0.f};
    for (int nt = 0; nt < 16; nt++) {
        bf16x8 bfrag = *(const bf16x8*)&Kl[nt * 16 + l15][quad * 8];
        f32x4 s = {0.f, 0.f, 0.f, 0.f};
        s = __builtin_amdgcn_mfma_f32_16x16x32_bf16(afrag, bfrag, s, 0, 0, 0);
        #pragma unroll
        for (int reg = 0; reg < 4; reg++) {
            const int q  = quad * 4 + reg;            // row in wave tile
            const int gq = wave * 16 + q;
            const int rqr = gq >> 3, rqc = gq & 7;
            const float rb = btab[(rqr - nt + 15) * 23 + (rqc - l15 + 15)];
            const float pv = __expf(s[reg] + rb - Mshift);
            lsum[reg] += pv;
            Pl[wave][q][(nt * 16 + l15) ^ ((q & 12) << 2)] = f2bf(pv);
        }
    }
    #pragma unroll
    for (int reg = 0; reg < 4; reg++) {
        float v = lsum[reg];
        v += __shfl_xor(v, 1); v += __shfl_xor(v, 2);
        v += __shfl_xor(v, 4); v += __shfl_xor(v, 8);
        lsum[reg] = 1.0f / v;
    }

    // ---- O = P.V ----
    f32x4 d0 = {0.f, 0.f, 0.f, 0.f};
    f32x4 d1 = {0.f, 0.f, 0.f, 0.f};
    #pragma unroll
    for (int ch = 0; ch < 8; ch++) {
        bf16x8 pa = *(const bf16x8*)&Pl[wave][l15][(ch * 32 + quad * 8) ^ ((l15 & 12) << 2)];
        bf16x8 b0 = *(const bf16x8*)&Vt[l15][ch * 32 + quad * 8];
        bf16x8 b1 = *(const bf16x8*)&Vt[l15 + 16][ch * 32 + quad * 8];
        d0 = __builtin_amdgcn_mfma_f32_16x16x32_bf16(pa, b0, d0, 0, 0, 0);
        d1 = __builtin_amdgcn_mfma_f32_16x16x32_bf16(pa, b1, d1, 0, 0, 0);
    }

    // ---- epilogue ----
    #pragma unroll
    for (int reg = 0; reg < 4; reg++) {
        const int gq = wave * 16 + quad * 4 + reg;
        const int oqr = gq >> 3, oqc = gq & 7;
        const int oy = wy * 8 + oqr, ox = wx * 8 + oqc;
        _Float16* op = out + (((size_t)(b * 128 + oy) * 128 + ox) * CC) + h * HD;
        op[l15]      = (_Float16)(d0[reg] * lsum[reg]);
        op[16 + l15] = (_Float16)(d1[reg] * lsum[reg]);
    }
}

// ---------------------------------------------------------------------------
extern "C" void kernel_launch(void* const* d_in, const int* in_sizes, int n_in,
                              void* d_out, int out_size, void* d_ws, size_t ws_size,
                              hipStream_t stream) {
    const float* x           = (const float*)d_in[0];
    const float* w_qkv       = (const float*)d_in[1];
    const float* w_dw        = (const float*)d_in[2];
    const float* ln_g        = (const float*)d_in[3];
    const float* ln_b        = (const float*)d_in[4];
    const float* q_bias      = (const float*)d_in[5];
    const float* v_bias      = (const float*)d_in[6];
    const float* logit_scale = (const float*)d_in[7];
    const float* cpb_w1      = (const float*)d_in[8];
    const float* cpb_b1      = (const float*)d_in[9];
    const float* cpb_w2      = (const float*)d_in[10];
    const float* w_proj      = (const float*)d_in[11];
    float* out = (float*)d_out;

    char* ws = (char*)d_ws;
    _Float16* xh     = (_Float16*)(ws);                          // 16.78 MB
    _Float16* qkv0h  = (_Float16*)(ws + 16777216);               // 50.33 MB
    _Float16* qkvh   = (_Float16*)(ws + 67108864);               // 50.33 MB
    _Float16* attnh  = (_Float16*)(ws + 117440512);              // 16.78 MB
    _Float16* wqkvT  = (_Float16*)(ws + 134217728);              // 0.39 MB
    _Float16* wprojT = (_Float16*)(ws + 134610944);              // 0.13 MB
    float*    btab   = (float*)   (ws + 134742016);              // 17 KB

    cpb_kernel<<<529, 64, 0, stream>>>(cpb_w1, cpb_b1, cpb_w2, btab);
    cvt_f32_f16<<<(NPIX * CC / 4 + 255) / 256, 256, 0, stream>>>(x, xh, NPIX * CC / 4);
    transpose_cvt<<<dim3(C3 / 32, CC / 32), 256, 0, stream>>>(w_qkv, wqkvT, CC, C3);
    transpose_cvt<<<dim3(CC / 32, CC / 32), 256, 0, stream>>>(w_proj, wprojT, CC, CC);

    // qkv0 = x @ w_qkv    (fp16 MFMA, fp16 out)
    gemm_f16<_Float16><<<dim3(C3 / 128, NPIX / 128), 256, 0, stream>>>(
        xh, wqkvT, qkv0h, NPIX, C3, CC);
    // depthwise 3x3 + LN + bias
    dwconv_ln<<<NPIX, 192, 0, stream>>>(qkv0h, w_dw, ln_g, ln_b, q_bias, v_bias,
                                        qkvh);
    // halo window attention
    attn_mfma<<<NWIN * NHEADS, 256, 0, stream>>>(qkvh, btab, logit_scale, attnh);
    // out = attn_out @ w_proj   (fp32 out)
    gemm_f16<float><<<dim3(CC / 128, NPIX / 128), 256, 0, stream>>>(
        attnh, wprojT, out, NPIX, CC, CC);
}

// Round 5
// 284.590 us; speedup vs baseline: 3.8429x; 1.0295x over previous
//
#include <hip/hip_runtime.h>
#include <hip/hip_bf16.h>
#include <hip/hip_fp16.h>
#include <cstddef>
#include <cstdint>

// Problem constants
#define BB 2
#define HH 128
#define WW 128
#define CC 256
#define WSZ 8
#define KWIN 16
#define NHEADS 8
#define HD 32
#define C3 768
#define NPIX 32768            // B*H*W
#define NWIN 512              // B * 16 * 16

typedef short    bf16x8 __attribute__((ext_vector_type(8)));
typedef _Float16 half8  __attribute__((ext_vector_type(8)));
typedef _Float16 half4v __attribute__((ext_vector_type(4)));
typedef float    f32x4  __attribute__((ext_vector_type(4)));

__device__ inline short f2bf(float f) {
    union { float f; unsigned u; } v; v.f = f;
    unsigned r = (v.u + 0x7fffu + ((v.u >> 16) & 1u)) >> 16;
    return (short)r;
}

__device__ inline void gload_lds16(const _Float16* g, _Float16* l) {
    __builtin_amdgcn_global_load_lds(
        (const __attribute__((address_space(1))) unsigned int*)g,
        (__attribute__((address_space(3))) unsigned int*)l, 16, 0, 0);
}

// ---------------------------------------------------------------------------
// CPB MLP: bias_tab[529][8] = sigmoid(relu(tab @ w1 + b1) @ w2) * 16
// ---------------------------------------------------------------------------
__global__ __launch_bounds__(64) void cpb_kernel(const float* __restrict__ w1,
                                                 const float* __restrict__ b1,
                                                 const float* __restrict__ w2,
                                                 float* __restrict__ btab) {
    const int e = blockIdx.x;          // 0..528
    const int i = e / 23, j = e % 23;
    const float inv_log8 = 1.0f / logf(8.0f);
    float c0 = (float)(i - 11) * (8.0f / 7.0f);
    float c1 = (float)(j - 11) * (8.0f / 7.0f);
    float f0 = copysignf(log1pf(fabsf(c0)) * inv_log8, c0);
    float f1 = copysignf(log1pf(fabsf(c1)) * inv_log8, c1);

    const int t = threadIdx.x;
    float acc[8] = {0.f,0.f,0.f,0.f,0.f,0.f,0.f,0.f};
    for (int kk = 0; kk < 8; kk++) {
        int k = kk * 64 + t;
        float hid = f0 * w1[k] + f1 * w1[512 + k] + b1[k];
        hid = fmaxf(hid, 0.f);
        #pragma unroll
        for (int h = 0; h < 8; h++) acc[h] += hid * w2[k * 8 + h];
    }
    #pragma unroll
    for (int h = 0; h < 8; h++) {
        #pragma unroll
        for (int off = 32; off >= 1; off >>= 1) acc[h] += __shfl_xor(acc[h], off);
    }
    if (t < 8) {
        float v = acc[t];
        btab[e * 8 + t] = 16.0f / (1.0f + expf(-v));
    }
}

// ---------------------------------------------------------------------------
// fp32 -> fp16 elementwise convert (4 elems/thread)
// ---------------------------------------------------------------------------
__global__ __launch_bounds__(256) void cvt_f32_f16(const float* __restrict__ src,
                                                   _Float16* __restrict__ dst,
                                                   int n4) {
    int i = blockIdx.x * 256 + threadIdx.x;
    if (i >= n4) return;
    float4 v = *(const float4*)(src + (size_t)i * 4);
    half4v o; o[0] = (_Float16)v.x; o[1] = (_Float16)v.y;
    o[2] = (_Float16)v.z; o[3] = (_Float16)v.w;
    *(half4v*)(dst + (size_t)i * 4) = o;
}

// ---------------------------------------------------------------------------
// transpose + convert: src fp32 [R][Cn] -> dst fp16 [Cn][R].  32x32 LDS tile.
// ---------------------------------------------------------------------------
__global__ __launch_bounds__(256) void transpose_cvt(const float* __restrict__ src,
                                                     _Float16* __restrict__ dst,
                                                     int R, int Cn) {
    __shared__ float t[32][33];
    const int bx = blockIdx.x, by = blockIdx.y;
    const int tx = threadIdx.x & 31, ty = threadIdx.x >> 5;
    #pragma unroll
    for (int i = 0; i < 4; i++) {
        int r = by * 32 + ty + i * 8;
        t[ty + i * 8][tx] = src[(size_t)r * Cn + bx * 32 + tx];
    }
    __syncthreads();
    #pragma unroll
    for (int i = 0; i < 4; i++) {
        int dr = bx * 32 + ty + i * 8;          // orig col
        dst[(size_t)dr * R + by * 32 + tx] = (_Float16)t[tx][ty + i * 8];
    }
}

// ---------------------------------------------------------------------------
// fp16 MFMA NT-GEMM:  C[M][N] = A[M][K] * Bt[N][K]^T, fp32 accumulate.
// 128x128 tile, BK=64, 256 threads (4 waves, 2x2 of 64x64).
// ---------------------------------------------------------------------------
template <typename OT>
__global__ __launch_bounds__(256) void gemm_f16(const _Float16* __restrict__ A,
                                                const _Float16* __restrict__ Bt,
                                                OT* __restrict__ C,
                                                int M, int N, int K) {
    __shared__ _Float16 Ash[128][64];
    __shared__ _Float16 Bsh[128][64];
    const int tid = threadIdx.x;
    const int wv = tid >> 6, ln = tid & 63;
    const int quad = ln >> 4, l15 = ln & 15;
    const int rowb = blockIdx.y * 128;
    const int colb = blockIdx.x * 128;
    const int wm = (wv >> 1) * 64, wn = (wv & 1) * 64;

    const int r8 = ln >> 3, g = ln & 7;
    const int kg = g ^ r8;                    // swizzled logical k-group

    f32x4 acc[4][4] = {};
    for (int k0 = 0; k0 < K; k0 += 64) {
        #pragma unroll
        for (int i = 0; i < 4; i++) {
            const int m = wv * 32 + i * 8 + r8;
            gload_lds16(A + (size_t)(rowb + m) * K + k0 + kg * 8,
                        &Ash[wv * 32 + i * 8][0]);
            gload_lds16(Bt + (size_t)(colb + m) * K + k0 + kg * 8,
                        &Bsh[wv * 32 + i * 8][0]);
        }
        __syncthreads();
        #pragma unroll
        for (int kk = 0; kk < 2; kk++) {
            const int phys = ((kk * 4 + quad) ^ (l15 & 7)) * 8;
            half8 a[4], b[4];
            #pragma unroll
            for (int i = 0; i < 4; i++)
                a[i] = *(const half8*)&Ash[wm + i * 16 + l15][phys];
            #pragma unroll
            for (int j = 0; j < 4; j++)
                b[j] = *(const half8*)&Bsh[wn + j * 16 + l15][phys];
            #pragma unroll
            for (int i = 0; i < 4; i++)
                #pragma unroll
                for (int j = 0; j < 4; j++)
                    acc[i][j] = __builtin_amdgcn_mfma_f32_16x16x32_f16(
                        a[i], b[j], acc[i][j], 0, 0, 0);
        }
        __syncthreads();
    }
    #pragma unroll
    for (int i = 0; i < 4; i++) {
        #pragma unroll
        for (int reg = 0; reg < 4; reg++) {
            const size_t row = rowb + wm + i * 16 + quad * 4 + reg;
            #pragma unroll
            for (int j = 0; j < 4; j++) {
                C[row * N + colb + wn + j * 16 + l15] = (OT)acc[i][j][reg];
            }
        }
    }
}

// ---------------------------------------------------------------------------
// Depthwise 3x3 conv (SAME) + LayerNorm(768) + qkv bias add.  fp16 in/out.
// v3: block = 8-pixel x-strip, 256 threads.  Stage 3x10x768 input halo +
// fp16 weights in LDS; thread (p = t&7, g = t>>3) computes 24 channels
// (g*8 + {0,256,512}) of pixel p via v_fma_mix.  All LDS b128 patterns are
// lane-uniform over 8 bank windows (minimum cycles).
// ---------------------------------------------------------------------------
__global__ __launch_bounds__(256) void dwconv_ln(const _Float16* __restrict__ in,
                                                 const float* __restrict__ wdw,
                                                 const float* __restrict__ g,
                                                 const float* __restrict__ bt,
                                                 const float* __restrict__ qb,
                                                 const float* __restrict__ vb,
                                                 _Float16* __restrict__ out) {
    __shared__ _Float16 S[3 * 10 * C3];   // input halo stage, 45 KB
    __shared__ _Float16 Wl[9 * C3];       // fp16 weights, 13.5 KB
    __shared__ float sred[4][8][2];

    const int t = threadIdx.x;
    const int pix0 = blockIdx.x * 8;
    const int b = pix0 >> 14, y = (pix0 >> 7) & 127, x0 = pix0 & 127;

    // ---- weights -> LDS (864 half8 units) ----
    for (int u = t; u < 864; u += 256) {
        const float4 w0 = *(const float4*)(wdw + u * 8);
        const float4 w1 = *(const float4*)(wdw + u * 8 + 4);
        half8 w;
        w[0] = (_Float16)w0.x; w[1] = (_Float16)w0.y;
        w[2] = (_Float16)w0.z; w[3] = (_Float16)w0.w;
        w[4] = (_Float16)w1.x; w[5] = (_Float16)w1.y;
        w[6] = (_Float16)w1.z; w[7] = (_Float16)w1.w;
        *(half8*)&Wl[u * 8] = w;
    }
    // ---- input halo -> LDS (2880 half8 units: [r][c][grp]) ----
    for (int u = t; u < 2880; u += 256) {
        const int r = u / 960, rem = u - r * 960;
        const int c = rem / 96, grp = rem - c * 96;
        const int yy = y + r - 1, xx = x0 + c - 1;
        half8 v = (half8)(_Float16)0;
        if ((unsigned)yy < 128u && (unsigned)xx < 128u)
            v = *(const half8*)(in + (((size_t)(b * 128 + yy) * 128 + xx) * C3)
                                + grp * 8);
        *(half8*)&S[u * 8] = v;
    }
    __syncthreads();

    // ---- conv: 24 channels per thread ----
    const int p = t & 7, gidx = t >> 3;     // pixel in strip, channel group
    float acc[3][8] = {};
    #pragma unroll
    for (int s = 0; s < 3; s++) {
        const int grp = gidx + s * 32;
        half8 w[9];
        #pragma unroll
        for (int tap = 0; tap < 9; tap++)
            w[tap] = *(const half8*)&Wl[(tap * 96 + grp) * 8];
        #pragma unroll
        for (int r = 0; r < 3; r++) {
            #pragma unroll
            for (int dx = 0; dx < 3; dx++) {
                const half8 v = *(const half8*)&S[((r * 10 + p + dx) * 96 + grp) * 8];
                const half8 wt = w[r * 3 + dx];
                #pragma unroll
                for (int i = 0; i < 8; i++)
                    acc[s][i] += (float)v[i] * (float)wt[i];
            }
        }
    }

    // ---- LayerNorm reduction over 768 ch of pixel p ----
    float ls = 0.f, lss = 0.f;
    #pragma unroll
    for (int s = 0; s < 3; s++)
        #pragma unroll
        for (int i = 0; i < 8; i++) { ls += acc[s][i]; lss += acc[s][i] * acc[s][i]; }
    // reduce over lanes sharing p (l & 7): xor 8,16,32
    ls  += __shfl_xor(ls, 8);  lss += __shfl_xor(lss, 8);
    ls  += __shfl_xor(ls, 16); lss += __shfl_xor(lss, 16);
    ls  += __shfl_xor(ls, 32); lss += __shfl_xor(lss, 32);
    const int wv = t >> 6, lnid = t & 63;
    if (lnid < 8) { sred[wv][lnid][0] = ls; sred[wv][lnid][1] = lss; }
    __syncthreads();
    const float Ssum  = sred[0][p][0] + sred[1][p][0] + sred[2][p][0] + sred[3][p][0];
    const float SSsum = sred[0][p][1] + sred[1][p][1] + sred[2][p][1] + sred[3][p][1];
    const float mu  = Ssum * (1.0f / 768.0f);
    const float var = SSsum * (1.0f / 768.0f) - mu * mu;
    const float rs  = rsqrtf(var + 1e-5f);

    // ---- scale/shift + q/v bias, store ----
    const size_t obase = (size_t)(pix0 + p) * C3;
    #pragma unroll
    for (int s = 0; s < 3; s++) {
        const int ch = gidx * 8 + s * 256;
        const float4 g0 = *(const float4*)(g + ch);
        const float4 g1 = *(const float4*)(g + ch + 4);
        const float4 b0 = *(const float4*)(bt + ch);
        const float4 b1 = *(const float4*)(bt + ch + 4);
        float gg[8] = {g0.x, g0.y, g0.z, g0.w, g1.x, g1.y, g1.z, g1.w};
        float bb[8] = {b0.x, b0.y, b0.z, b0.w, b1.x, b1.y, b1.z, b1.w};
        if (s == 0) {
            const float4 e0 = *(const float4*)(qb + ch);
            const float4 e1 = *(const float4*)(qb + ch + 4);
            bb[0] += e0.x; bb[1] += e0.y; bb[2] += e0.z; bb[3] += e0.w;
            bb[4] += e1.x; bb[5] += e1.y; bb[6] += e1.z; bb[7] += e1.w;
        } else if (s == 2) {
            const float4 e0 = *(const float4*)(vb + ch - 512);
            const float4 e1 = *(const float4*)(vb + ch - 512 + 4);
            bb[0] += e0.x; bb[1] += e0.y; bb[2] += e0.z; bb[3] += e0.w;
            bb[4] += e1.x; bb[5] += e1.y; bb[6] += e1.z; bb[7] += e1.w;
        }
        half8 o;
        #pragma unroll
        for (int i = 0; i < 8; i++)
            o[i] = (_Float16)((acc[s][i] - mu) * rs * gg[i] + bb[i]);
        *(half8*)(out + obase + ch) = o;
    }
}

// ---------------------------------------------------------------------------
// MFMA halo window attention (fp16 in/out, bf16 MFMA internals).
// ---------------------------------------------------------------------------
__global__ __launch_bounds__(256) void attn_mfma(const _Float16* __restrict__ qkv,
                                                 const float* __restrict__ bias_tab,
                                                 const float* __restrict__ logit_scale,
                                                 _Float16* __restrict__ out) {
    const int blk = blockIdx.x;
    const int h = blk & 7;
    const int wid = blk >> 3;
    const int b = wid >> 8;
    const int wy = (wid >> 4) & 15;
    const int wx = wid & 15;
    const int tid = threadIdx.x;
    const int wave = tid >> 6, lane = tid & 63;
    const int quad = lane >> 4, l15 = lane & 15;

    __shared__ short Kl[256][40];     // normalized K, bf16 bits, row-major
    __shared__ short Vt[32][264];     // V transposed [dim][key], bf16 bits
    __shared__ short Pl[4][16][256];  // per-wave P, XOR-swizzled keys
    __shared__ float btab[529];

    for (int e = tid; e < 529; e += 256) btab[e] = bias_tab[e * 8 + h];

    // ---- stage K (l2-normalized) and V (transposed), one key per thread ----
    {
        const int j = tid;                         // key 0..255
        const int kr = j >> 4, kcc = j & 15;
        const int gy = wy * 8 - 4 + kr, gx = wx * 8 - 4 + kcc;
        const bool inb = ((unsigned)gy < 128u) && ((unsigned)gx < 128u);
        const _Float16* p = qkv +
            (((size_t)(b * 128 + (inb ? gy : 0)) * 128 + (inb ? gx : 0)) * C3) +
            256 + h * HD;
        float kreg[32];
        float s2 = 0.f;
        #pragma unroll
        for (int d8 = 0; d8 < 32; d8 += 8) {
            half8 kk, vv;
            if (inb) { kk = *(const half8*)(p + d8); vv = *(const half8*)(p + 256 + d8); }
            else     { kk = (half8)(_Float16)0;      vv = (half8)(_Float16)0; }
            #pragma unroll
            for (int u = 0; u < 8; u++) {
                float kf = (float)kk[u];
                kreg[d8 + u] = kf;
                s2 += kf * kf;
                Vt[d8 + u][j] = f2bf((float)vv[u]);
            }
        }
        const float r = rsqrtf(fmaxf(s2, 1.55e-5f));
        #pragma unroll
        for (int d = 0; d < 32; d++) Kl[j][d] = f2bf(kreg[d] * r);
    }
    __syncthreads();

    // ---- per-wave Q A-fragment: A[m=l15][k=quad*8+j] ----
    const float lscale = __expf(fminf(logit_scale[h], 4.60517019f)); // ln(100)
    const float Mshift = lscale + 16.0f;
    const int qrow = wave * 16 + l15;
    const int qr = qrow >> 3, qc = qrow & 7;
    const int qy = wy * 8 + qr, qx = wx * 8 + qc;
    bf16x8 afrag;
    {
        const _Float16* qp = qkv + (((size_t)(b * 128 + qy) * 128 + qx) * C3) + h * HD + quad * 8;
        half8 q8 = *(const half8*)qp;
        float qf[8];
        float s2 = 0.f;
        #pragma unroll
        for (int u = 0; u < 8; u++) { qf[u] = (float)q8[u]; s2 += qf[u] * qf[u]; }
        s2 += __shfl_xor(s2, 16);
        s2 += __shfl_xor(s2, 32);
        const float rq = rsqrtf(fmaxf(s2, 1.55e-5f)) * lscale;
        #pragma unroll
        for (int u = 0; u < 8; u++) afrag[u] = f2bf(qf[u] * rq);
    }

    // ---- S = Q.K^T tiles, exp, row-sums, P -> LDS ----
    float lsum[4] = {0.f, 0.f, 0.f, 0.f};
    for (int nt = 0; nt < 16; nt++) {
        bf16x8 bfrag = *(const bf16x8*)&Kl[nt * 16 + l15][quad * 8];
        f32x4 s = {0.f, 0.f, 0.f, 0.f};
        s = __builtin_amdgcn_mfma_f32_16x16x32_bf16(afrag, bfrag, s, 0, 0, 0);
        #pragma unroll
        for (int reg = 0; reg < 4; reg++) {
            const int q  = quad * 4 + reg;            // row in wave tile
            const int gq = wave * 16 + q;
            const int rqr = gq >> 3, rqc = gq & 7;
            const float rb = btab[(rqr - nt + 15) * 23 + (rqc - l15 + 15)];
            const float pv = __expf(s[reg] + rb - Mshift);
            lsum[reg] += pv;
            Pl[wave][q][(nt * 16 + l15) ^ ((q & 12) << 2)] = f2bf(pv);
        }
    }
    #pragma unroll
    for (int reg = 0; reg < 4; reg++) {
        float v = lsum[reg];
        v += __shfl_xor(v, 1); v += __shfl_xor(v, 2);
        v += __shfl_xor(v, 4); v += __shfl_xor(v, 8);
        lsum[reg] = 1.0f / v;
    }

    // ---- O = P.V ----
    f32x4 d0 = {0.f, 0.f, 0.f, 0.f};
    f32x4 d1 = {0.f, 0.f, 0.f, 0.f};
    #pragma unroll
    for (int ch = 0; ch < 8; ch++) {
        bf16x8 pa = *(const bf16x8*)&Pl[wave][l15][(ch * 32 + quad * 8) ^ ((l15 & 12) << 2)];
        bf16x8 b0 = *(const bf16x8*)&Vt[l15][ch * 32 + quad * 8];
        bf16x8 b1 = *(const bf16x8*)&Vt[l15 + 16][ch * 32 + quad * 8];
        d0 = __builtin_amdgcn_mfma_f32_16x16x32_bf16(pa, b0, d0, 0, 0, 0);
        d1 = __builtin_amdgcn_mfma_f32_16x16x32_bf16(pa, b1, d1, 0, 0, 0);
    }

    // ---- epilogue ----
    #pragma unroll
    for (int reg = 0; reg < 4; reg++) {
        const int gq = wave * 16 + quad * 4 + reg;
        const int oqr = gq >> 3, oqc = gq & 7;
        const int oy = wy * 8 + oqr, ox = wx * 8 + oqc;
        _Float16* op = out + (((size_t)(b * 128 + oy) * 128 + ox) * CC) + h * HD;
        op[l15]      = (_Float16)(d0[reg] * lsum[reg]);
        op[16 + l15] = (_Float16)(d1[reg] * lsum[reg]);
    }
}

// ---------------------------------------------------------------------------
extern "C" void kernel_launch(void* const* d_in, const int* in_sizes, int n_in,
                              void* d_out, int out_size, void* d_ws, size_t ws_size,
                              hipStream_t stream) {
    const float* x           = (const float*)d_in[0];
    const float* w_qkv       = (const float*)d_in[1];
    const float* w_dw        = (const float*)d_in[2];
    const float* ln_g        = (const float*)d_in[3];
    const float* ln_b        = (const float*)d_in[4];
    const float* q_bias      = (const float*)d_in[5];
    const float* v_bias      = (const float*)d_in[6];
    const float* logit_scale = (const float*)d_in[7];
    const float* cpb_w1      = (const float*)d_in[8];
    const float* cpb_b1      = (const float*)d_in[9];
    const float* cpb_w2      = (const float*)d_in[10];
    const float* w_proj      = (const float*)d_in[11];
    float* out = (float*)d_out;

    char* ws = (char*)d_ws;
    _Float16* xh     = (_Float16*)(ws);                          // 16.78 MB
    _Float16* qkv0h  = (_Float16*)(ws + 16777216);               // 50.33 MB
    _Float16* qkvh   = (_Float16*)(ws + 67108864);               // 50.33 MB
    _Float16* attnh  = (_Float16*)(ws + 117440512);              // 16.78 MB
    _Float16* wqkvT  = (_Float16*)(ws + 134217728);              // 0.39 MB
    _Float16* wprojT = (_Float16*)(ws + 134610944);              // 0.13 MB
    float*    btab   = (float*)   (ws + 134742016);              // 17 KB

    cpb_kernel<<<529, 64, 0, stream>>>(cpb_w1, cpb_b1, cpb_w2, btab);
    cvt_f32_f16<<<(NPIX * CC / 4 + 255) / 256, 256, 0, stream>>>(x, xh, NPIX * CC / 4);
    transpose_cvt<<<dim3(C3 / 32, CC / 32), 256, 0, stream>>>(w_qkv, wqkvT, CC, C3);
    transpose_cvt<<<dim3(CC / 32, CC / 32), 256, 0, stream>>>(w_proj, wprojT, CC, CC);

    // qkv0 = x @ w_qkv    (fp16 MFMA, fp16 out)
    gemm_f16<_Float16><<<dim3(C3 / 128, NPIX / 128), 256, 0, stream>>>(
        xh, wqkvT, qkv0h, NPIX, C3, CC);
    // depthwise 3x3 + LN + bias  (8-pixel strips)
    dwconv_ln<<<NPIX / 8, 256, 0, stream>>>(qkv0h, w_dw, ln_g, ln_b, q_bias,
                                            v_bias, qkvh);
    // halo window attention
    attn_mfma<<<NWIN * NHEADS, 256, 0, stream>>>(qkvh, btab, logit_scale, attnh);
    // out = attn_out @ w_proj   (fp32 out)
    gemm_f16<float><<<dim3(CC / 128, NPIX / 128), 256, 0, stream>>>(
        attnh, wprojT, out, NPIX, CC, CC);
}

// Round 8
// 253.135 us; speedup vs baseline: 4.3205x; 1.1243x over previous
//
#include <hip/hip_runtime.h>
#include <hip/hip_bf16.h>
#include <hip/hip_fp16.h>
#include <cstddef>
#include <cstdint>

// Problem constants
#define BB 2
#define HH 128
#define WW 128
#define CC 256
#define WSZ 8
#define KWIN 16
#define NHEADS 8
#define HD 32
#define C3 768
#define NPIX 32768            // B*H*W
#define NWIN 512              // B * 16 * 16

typedef short    bf16x8 __attribute__((ext_vector_type(8)));
typedef _Float16 half8  __attribute__((ext_vector_type(8)));
typedef float    f32x4  __attribute__((ext_vector_type(4)));

__device__ inline short f2bf(float f) {
    union { float f; unsigned u; } v; v.f = f;
    unsigned r = (v.u + 0x7fffu + ((v.u >> 16) & 1u)) >> 16;
    return (short)r;
}

__device__ inline void gload_lds16(const _Float16* g, _Float16* l) {
    __builtin_amdgcn_global_load_lds(
        (const __attribute__((address_space(1))) unsigned int*)g,
        (__attribute__((address_space(3))) unsigned int*)l, 16, 0, 0);
}

// ---------------------------------------------------------------------------
// CPB MLP: bias_tab[529][8] = sigmoid(relu(tab @ w1 + b1) @ w2) * 16
// ---------------------------------------------------------------------------
__global__ __launch_bounds__(64) void cpb_kernel(const float* __restrict__ w1,
                                                 const float* __restrict__ b1,
                                                 const float* __restrict__ w2,
                                                 float* __restrict__ btab) {
    const int e = blockIdx.x;          // 0..528
    const int i = e / 23, j = e % 23;
    const float inv_log8 = 1.0f / logf(8.0f);
    float c0 = (float)(i - 11) * (8.0f / 7.0f);
    float c1 = (float)(j - 11) * (8.0f / 7.0f);
    float f0 = copysignf(log1pf(fabsf(c0)) * inv_log8, c0);
    float f1 = copysignf(log1pf(fabsf(c1)) * inv_log8, c1);

    const int t = threadIdx.x;
    float acc[8] = {0.f,0.f,0.f,0.f,0.f,0.f,0.f,0.f};
    for (int kk = 0; kk < 8; kk++) {
        int k = kk * 64 + t;
        float hid = f0 * w1[k] + f1 * w1[512 + k] + b1[k];
        hid = fmaxf(hid, 0.f);
        #pragma unroll
        for (int h = 0; h < 8; h++) acc[h] += hid * w2[k * 8 + h];
    }
    #pragma unroll
    for (int h = 0; h < 8; h++) {
        #pragma unroll
        for (int off = 32; off >= 1; off >>= 1) acc[h] += __shfl_xor(acc[h], off);
    }
    if (t < 8) {
        float v = acc[t];
        btab[e * 8 + t] = 16.0f / (1.0f + expf(-v));
    }
}

// ---------------------------------------------------------------------------
// depthwise weights fp32 -> fp16 table (9*768 elems)
// ---------------------------------------------------------------------------
__global__ __launch_bounds__(256) void cvt_wdw(const float* __restrict__ src,
                                               _Float16* __restrict__ dst) {
    int i = blockIdx.x * 256 + threadIdx.x;
    if (i < 9 * C3) dst[i] = (_Float16)src[i];
}

// ---------------------------------------------------------------------------
// transpose + convert: src fp32 [R][Cn] -> dst fp16 [Cn][R].  32x32 LDS tile.
// ---------------------------------------------------------------------------
__global__ __launch_bounds__(256) void transpose_cvt(const float* __restrict__ src,
                                                     _Float16* __restrict__ dst,
                                                     int R, int Cn) {
    __shared__ float t[32][33];
    const int bx = blockIdx.x, by = blockIdx.y;
    const int tx = threadIdx.x & 31, ty = threadIdx.x >> 5;
    #pragma unroll
    for (int i = 0; i < 4; i++) {
        int r = by * 32 + ty + i * 8;
        t[ty + i * 8][tx] = src[(size_t)r * Cn + bx * 32 + tx];
    }
    __syncthreads();
    #pragma unroll
    for (int i = 0; i < 4; i++) {
        int dr = bx * 32 + ty + i * 8;          // orig col
        dst[(size_t)dr * R + by * 32 + tx] = (_Float16)t[tx][ty + i * 8];
    }
}

// ---------------------------------------------------------------------------
// fp16 MFMA NT-GEMM:  C[M][N] = A[M][K] * Bt[N][K]^T, fp32 accumulate.
// 128x128 tile, BK=64, 256 threads (4 waves, 2x2 of 64x64).
// LDS layout contract: physical k-slot p at row m holds logical group
// p ^ (m&7); fragment reads undo via phys = logical ^ (l15&7).
// ---------------------------------------------------------------------------
template <typename OT>
__global__ __launch_bounds__(256) void gemm_f16(const _Float16* __restrict__ A,
                                                const _Float16* __restrict__ Bt,
                                                OT* __restrict__ C,
                                                int M, int N, int K) {
    __shared__ _Float16 Ash[128][64];
    __shared__ _Float16 Bsh[128][64];
    const int tid = threadIdx.x;
    const int wv = tid >> 6, ln = tid & 63;
    const int quad = ln >> 4, l15 = ln & 15;
    const int rowb = blockIdx.y * 128;
    const int colb = blockIdx.x * 128;
    const int wm = (wv >> 1) * 64, wn = (wv & 1) * 64;

    const int r8 = ln >> 3, g = ln & 7;
    const int kg = g ^ r8;                    // swizzled logical k-group

    f32x4 acc[4][4] = {};
    for (int k0 = 0; k0 < K; k0 += 64) {
        #pragma unroll
        for (int i = 0; i < 4; i++) {
            const int m = wv * 32 + i * 8 + r8;
            gload_lds16(A + (size_t)(rowb + m) * K + k0 + kg * 8,
                        &Ash[wv * 32 + i * 8][0]);
            gload_lds16(Bt + (size_t)(colb + m) * K + k0 + kg * 8,
                        &Bsh[wv * 32 + i * 8][0]);
        }
        __syncthreads();
        #pragma unroll
        for (int kk = 0; kk < 2; kk++) {
            const int phys = ((kk * 4 + quad) ^ (l15 & 7)) * 8;
            half8 a[4], b[4];
            #pragma unroll
            for (int i = 0; i < 4; i++)
                a[i] = *(const half8*)&Ash[wm + i * 16 + l15][phys];
            #pragma unroll
            for (int j = 0; j < 4; j++)
                b[j] = *(const half8*)&Bsh[wn + j * 16 + l15][phys];
            #pragma unroll
            for (int i = 0; i < 4; i++)
                #pragma unroll
                for (int j = 0; j < 4; j++)
                    acc[i][j] = __builtin_amdgcn_mfma_f32_16x16x32_f16(
                        a[i], b[j], acc[i][j], 0, 0, 0);
        }
        __syncthreads();
    }
    #pragma unroll
    for (int i = 0; i < 4; i++) {
        #pragma unroll
        for (int reg = 0; reg < 4; reg++) {
            const size_t row = rowb + wm + i * 16 + quad * 4 + reg;
            #pragma unroll
            for (int j = 0; j < 4; j++) {
                C[row * N + colb + wn + j * 16 + l15] = (OT)acc[i][j][reg];
            }
        }
    }
}

// ---------------------------------------------------------------------------
// qkv GEMM with fused fp32->fp16 A conversion (A = x fp32 [M][K]).
// Manual A staging must honor the layout contract (phys p holds logical
// p^(m&7)): lane loads logical group g and writes phys slot g^r8 — correct
// AND conflict-free (fixed g, varying r8 sweeps all 8 bank windows).
// ---------------------------------------------------------------------------
__global__ __launch_bounds__(256) void gemm_qkv(const float* __restrict__ A,
                                                const _Float16* __restrict__ Bt,
                                                _Float16* __restrict__ C,
                                                int M, int N, int K) {
    __shared__ _Float16 Ash[128][64];
    __shared__ _Float16 Bsh[128][64];
    const int tid = threadIdx.x;
    const int wv = tid >> 6, ln = tid & 63;
    const int quad = ln >> 4, l15 = ln & 15;
    const int rowb = blockIdx.y * 128;
    const int colb = blockIdx.x * 128;
    const int wm = (wv >> 1) * 64, wn = (wv & 1) * 64;
    const int r8 = ln >> 3, g = ln & 7;
    const int kg = g ^ r8;

    f32x4 acc[4][4] = {};
    for (int k0 = 0; k0 < K; k0 += 64) {
        #pragma unroll
        for (int i = 0; i < 4; i++) {
            const int m = wv * 32 + i * 8 + r8;
            // load LOGICAL group g, write PHYSICAL slot g^r8
            const float* ap = A + (size_t)(rowb + m) * K + k0 + g * 8;
            const float4 a0 = *(const float4*)ap;
            const float4 a1 = *(const float4*)(ap + 4);
            half8 hv;
            hv[0] = (_Float16)a0.x; hv[1] = (_Float16)a0.y;
            hv[2] = (_Float16)a0.z; hv[3] = (_Float16)a0.w;
            hv[4] = (_Float16)a1.x; hv[5] = (_Float16)a1.y;
            hv[6] = (_Float16)a1.z; hv[7] = (_Float16)a1.w;
            *(half8*)&Ash[wv * 32 + i * 8 + r8][kg * 8] = hv;
            gload_lds16(Bt + (size_t)(colb + m) * K + k0 + kg * 8,
                        &Bsh[wv * 32 + i * 8][0]);
        }
        __syncthreads();
        #pragma unroll
        for (int kk = 0; kk < 2; kk++) {
            const int phys = ((kk * 4 + quad) ^ (l15 & 7)) * 8;
            half8 a[4], b[4];
            #pragma unroll
            for (int i = 0; i < 4; i++)
                a[i] = *(const half8*)&Ash[wm + i * 16 + l15][phys];
            #pragma unroll
            for (int j = 0; j < 4; j++)
                b[j] = *(const half8*)&Bsh[wn + j * 16 + l15][phys];
            #pragma unroll
            for (int i = 0; i < 4; i++)
                #pragma unroll
                for (int j = 0; j < 4; j++)
                    acc[i][j] = __builtin_amdgcn_mfma_f32_16x16x32_f16(
                        a[i], b[j], acc[i][j], 0, 0, 0);
        }
        __syncthreads();
    }
    #pragma unroll
    for (int i = 0; i < 4; i++) {
        #pragma unroll
        for (int reg = 0; reg < 4; reg++) {
            const size_t row = rowb + wm + i * 16 + quad * 4 + reg;
            #pragma unroll
            for (int j = 0; j < 4; j++) {
                C[row * N + colb + wn + j * 16 + l15] = (_Float16)acc[i][j][reg];
            }
        }
    }
}

// ---------------------------------------------------------------------------
// Depthwise 3x3 conv (SAME) + LayerNorm(768) + qkv bias add.
// v4: 8-pixel strip, 256 threads.  Input halo staged in LDS with column-XOR
// swizzle (phys = (u&~7)|((u^c)&7)) so each 8-lane phase sweeps all 8 bank
// windows -> conflict-free conv reads.  Weights from fp16 global table (L1).
// Output: q,k thirds fp16; v third stored as BF16 BITS (consumed by attn PV).
// ---------------------------------------------------------------------------
__global__ __launch_bounds__(256) void dwconv_ln(const _Float16* __restrict__ in,
                                                 const _Float16* __restrict__ wdwh,
                                                 const float* __restrict__ g,
                                                 const float* __restrict__ bt,
                                                 const float* __restrict__ qb,
                                                 const float* __restrict__ vb,
                                                 _Float16* __restrict__ out) {
    __shared__ _Float16 S[2880 * 8];      // 45 KB, swizzled half8 units
    __shared__ float sred[4][8][2];

    const int t = threadIdx.x;
    const int pix0 = blockIdx.x * 8;
    const int b = pix0 >> 14, y = (pix0 >> 7) & 127, x0 = pix0 & 127;

    // ---- input halo -> LDS (2880 units: u = (r*10+c)*96 + grp) ----
    for (int u = t; u < 2880; u += 256) {
        const int r = u / 960, rem = u - r * 960;
        const int c = rem / 96, grp = rem - c * 96;
        const int yy = y + r - 1, xx = x0 + c - 1;
        half8 v = (half8)(_Float16)0;
        if ((unsigned)yy < 128u && (unsigned)xx < 128u)
            v = *(const half8*)(in + (((size_t)(b * 128 + yy) * 128 + xx) * C3)
                                + grp * 8);
        const int phys = (u & ~7) | ((u ^ c) & 7);
        *(half8*)&S[phys * 8] = v;
    }
    __syncthreads();

    // ---- conv: thread (p = t&7, gidx = t>>3) does 24 ch of pixel p ----
    const int p = t & 7, gidx = t >> 3;
    float acc[3][8] = {};
    #pragma unroll
    for (int s = 0; s < 3; s++) {
        const int grp = gidx + s * 32;
        half8 w[9];
        #pragma unroll
        for (int tap = 0; tap < 9; tap++)
            w[tap] = *(const half8*)(wdwh + (tap * 96 + grp) * 8);
        #pragma unroll
        for (int r = 0; r < 3; r++) {
            #pragma unroll
            for (int dx = 0; dx < 3; dx++) {
                const int c = p + dx;
                const int u = (r * 10 + c) * 96 + grp;
                const int phys = (u & ~7) | ((u ^ c) & 7);
                const half8 v = *(const half8*)&S[phys * 8];
                const half8 wt = w[r * 3 + dx];
                #pragma unroll
                for (int i = 0; i < 8; i++)
                    acc[s][i] += (float)v[i] * (float)wt[i];
            }
        }
    }

    // ---- LayerNorm reduction over 768 ch of pixel p ----
    float ls = 0.f, lss = 0.f;
    #pragma unroll
    for (int s = 0; s < 3; s++)
        #pragma unroll
        for (int i = 0; i < 8; i++) { ls += acc[s][i]; lss += acc[s][i] * acc[s][i]; }
    ls  += __shfl_xor(ls, 8);  lss += __shfl_xor(lss, 8);
    ls  += __shfl_xor(ls, 16); lss += __shfl_xor(lss, 16);
    ls  += __shfl_xor(ls, 32); lss += __shfl_xor(lss, 32);
    const int wv = t >> 6, lnid = t & 63;
    if (lnid < 8) { sred[wv][lnid][0] = ls; sred[wv][lnid][1] = lss; }
    __syncthreads();
    const float Ssum  = sred[0][p][0] + sred[1][p][0] + sred[2][p][0] + sred[3][p][0];
    const float SSsum = sred[0][p][1] + sred[1][p][1] + sred[2][p][1] + sred[3][p][1];
    const float mu  = Ssum * (1.0f / 768.0f);
    const float var = SSsum * (1.0f / 768.0f) - mu * mu;
    const float rs  = rsqrtf(var + 1e-5f);

    // ---- scale/shift + q/v bias, store (v third as bf16 bits) ----
    const size_t obase = (size_t)(pix0 + p) * C3;
    #pragma unroll
    for (int s = 0; s < 3; s++) {
        const int ch = gidx * 8 + s * 256;
        const float4 g0 = *(const float4*)(g + ch);
        const float4 g1 = *(const float4*)(g + ch + 4);
        const float4 b0 = *(const float4*)(bt + ch);
        const float4 b1 = *(const float4*)(bt + ch + 4);
        float gg[8] = {g0.x, g0.y, g0.z, g0.w, g1.x, g1.y, g1.z, g1.w};
        float bb[8] = {b0.x, b0.y, b0.z, b0.w, b1.x, b1.y, b1.z, b1.w};
        if (s == 0) {
            const float4 e0 = *(const float4*)(qb + ch);
            const float4 e1 = *(const float4*)(qb + ch + 4);
            bb[0] += e0.x; bb[1] += e0.y; bb[2] += e0.z; bb[3] += e0.w;
            bb[4] += e1.x; bb[5] += e1.y; bb[6] += e1.z; bb[7] += e1.w;
        } else if (s == 2) {
            const float4 e0 = *(const float4*)(vb + ch - 512);
            const float4 e1 = *(const float4*)(vb + ch - 512 + 4);
            bb[0] += e0.x; bb[1] += e0.y; bb[2] += e0.z; bb[3] += e0.w;
            bb[4] += e1.x; bb[5] += e1.y; bb[6] += e1.z; bb[7] += e1.w;
        }
        if (s == 2) {
            bf16x8 o;
            #pragma unroll
            for (int i = 0; i < 8; i++)
                o[i] = f2bf((acc[s][i] - mu) * rs * gg[i] + bb[i]);
            *(bf16x8*)((short*)(out + obase + ch)) = o;
        } else {
            half8 o;
            #pragma unroll
            for (int i = 0; i < 8; i++)
                o[i] = (_Float16)((acc[s][i] - mu) * rs * gg[i] + bb[i]);
            *(half8*)(out + obase + ch) = o;
        }
    }
}

// ---------------------------------------------------------------------------
// MFMA halo window attention v3.
// QK^T in fp16 MFMA (K staged directly in B-fragment layout, b128 writes);
// P/V in bf16 (V pre-converted to bf16 bits by dwconv -> zero-VALU staging).
// Keys processed in two 128-chunks (Pl halved -> 51 KB LDS -> 3 blocks/CU).
// btab holds rb - M (shift folded).  Exact softmax, static shift M=scale+16.
// ---------------------------------------------------------------------------
__global__ __launch_bounds__(256) void attn_mfma(const _Float16* __restrict__ qkv,
                                                 const float* __restrict__ bias_tab,
                                                 const float* __restrict__ logit_scale,
                                                 _Float16* __restrict__ out) {
    const int blk = blockIdx.x;
    const int h = blk & 7;
    const int wid = blk >> 3;
    const int b = wid >> 8;
    const int wy = (wid >> 4) & 15;
    const int wx = wid & 15;
    const int tid = threadIdx.x;
    const int wave = tid >> 6, lane = tid & 63;
    const int quad = lane >> 4, l15 = lane & 15;

    __shared__ _Float16 Bf[16 * 64 * 8];  // K in B-frag layout, 16 KB
    __shared__ short Vt[32][264];         // V^T bf16 bits, 16.9 KB
    __shared__ short Pl[4][16][128];      // per-wave P chunk, 16 KB
    __shared__ float btab[529];           // rb - M

    const float lscale = __expf(fminf(logit_scale[h], 4.60517019f)); // ln(100)
    const float Mshift = lscale + 16.0f;
    for (int e = tid; e < 529; e += 256) btab[e] = bias_tab[e * 8 + h] - Mshift;

    // ---- stage K (normalize -> f16 frag layout) and V (bf16 bits), 1 key/thread
    {
        const int j = tid;                         // key 0..255
        const int kr = j >> 4, kcc = j & 15;
        const int gy = wy * 8 - 4 + kr, gx = wx * 8 - 4 + kcc;
        const bool inb = ((unsigned)gy < 128u) && ((unsigned)gx < 128u);
        const _Float16* p = qkv +
            (((size_t)(b * 128 + (inb ? gy : 0)) * 128 + (inb ? gx : 0)) * C3) +
            256 + h * HD;
        const short* vp = (const short*)(p + 256);
        float kreg[32];
        float s2 = 0.f;
        #pragma unroll
        for (int d8 = 0; d8 < 4; d8++) {
            half8 kk;
            bf16x8 vv;
            if (inb) { kk = *(const half8*)(p + d8 * 8); vv = *(const bf16x8*)(vp + d8 * 8); }
            else     { kk = (half8)(_Float16)0;          vv = (bf16x8)(short)0; }
            #pragma unroll
            for (int u = 0; u < 8; u++) {
                const float kf = (float)kk[u];
                kreg[d8 * 8 + u] = kf;
                s2 += kf * kf;
                Vt[d8 * 8 + u][j] = vv[u];
            }
        }
        const float r = rsqrtf(fmaxf(s2, 1.55e-5f));
        #pragma unroll
        for (int d8 = 0; d8 < 4; d8++) {
            half8 hv;
            #pragma unroll
            for (int u = 0; u < 8; u++)
                hv[u] = (_Float16)(kreg[d8 * 8 + u] * r);
            // B-frag slot: tile = j>>4, lane = d8*16 + (j&15)
            *(half8*)&Bf[(((j >> 4) * 64) + d8 * 16 + (j & 15)) * 8] = hv;
        }
    }
    __syncthreads();

    // ---- per-wave Q A-fragment (f16): A[m=l15][k=quad*8+u] ----
    const int qrow = wave * 16 + l15;
    const int qr = qrow >> 3, qc = qrow & 7;
    const int qy = wy * 8 + qr, qx = wx * 8 + qc;
    half8 afrag;
    {
        const _Float16* qp = qkv + (((size_t)(b * 128 + qy) * 128 + qx) * C3) + h * HD + quad * 8;
        half8 q8 = *(const half8*)qp;
        float qf[8];
        float s2 = 0.f;
        #pragma unroll
        for (int u = 0; u < 8; u++) { qf[u] = (float)q8[u]; s2 += qf[u] * qf[u]; }
        s2 += __shfl_xor(s2, 16);
        s2 += __shfl_xor(s2, 32);
        const float rq = rsqrtf(fmaxf(s2, 1.55e-5f)) * lscale;
        #pragma unroll
        for (int u = 0; u < 8; u++) afrag[u] = (_Float16)(qf[u] * rq);
    }

    // ---- two 128-key halves: S tiles -> exp -> Pl -> PV ----
    float lsum[4] = {0.f, 0.f, 0.f, 0.f};
    f32x4 d0 = {0.f, 0.f, 0.f, 0.f};
    f32x4 d1 = {0.f, 0.f, 0.f, 0.f};
    #pragma unroll
    for (int hf = 0; hf < 2; hf++) {
        #pragma unroll
        for (int ntl = 0; ntl < 8; ntl++) {
            const int nt = hf * 8 + ntl;
            half8 bfrag = *(const half8*)&Bf[(nt * 64 + lane) * 8];
            f32x4 s = {0.f, 0.f, 0.f, 0.f};
            s = __builtin_amdgcn_mfma_f32_16x16x32_f16(afrag, bfrag, s, 0, 0, 0);
            #pragma unroll
            for (int reg = 0; reg < 4; reg++) {
                const int q  = quad * 4 + reg;
                const int gq = wave * 16 + q;
                const int rqr = gq >> 3, rqc = gq & 7;
                const float rb = btab[(rqr - nt + 15) * 23 + (rqc - l15 + 15)];
                const float pv = __expf(s[reg] + rb);
                lsum[reg] += pv;
                Pl[wave][q][(ntl * 16 + l15) ^ ((q & 12) << 2)] = f2bf(pv);
            }
        }
        #pragma unroll
        for (int ch = 0; ch < 4; ch++) {
            const int kb = hf * 128 + ch * 32;
            bf16x8 pa = *(const bf16x8*)&Pl[wave][l15][(ch * 32 + quad * 8) ^ ((l15 & 12) << 2)];
            bf16x8 b0 = *(const bf16x8*)&Vt[l15][kb + quad * 8];
            bf16x8 b1 = *(const bf16x8*)&Vt[l15 + 16][kb + quad * 8];
            d0 = __builtin_amdgcn_mfma_f32_16x16x32_bf16(pa, b0, d0, 0, 0, 0);
            d1 = __builtin_amdgcn_mfma_f32_16x16x32_bf16(pa, b1, d1, 0, 0, 0);
        }
    }
    #pragma unroll
    for (int reg = 0; reg < 4; reg++) {
        float v = lsum[reg];
        v += __shfl_xor(v, 1); v += __shfl_xor(v, 2);
        v += __shfl_xor(v, 4); v += __shfl_xor(v, 8);
        lsum[reg] = 1.0f / v;
    }

    // ---- epilogue ----
    #pragma unroll
    for (int reg = 0; reg < 4; reg++) {
        const int gq = wave * 16 + quad * 4 + reg;
        const int oqr = gq >> 3, oqc = gq & 7;
        const int oy = wy * 8 + oqr, ox = wx * 8 + oqc;
        _Float16* op = out + (((size_t)(b * 128 + oy) * 128 + ox) * CC) + h * HD;
        op[l15]      = (_Float16)(d0[reg] * lsum[reg]);
        op[16 + l15] = (_Float16)(d1[reg] * lsum[reg]);
    }
}

// ---------------------------------------------------------------------------
extern "C" void kernel_launch(void* const* d_in, const int* in_sizes, int n_in,
                              void* d_out, int out_size, void* d_ws, size_t ws_size,
                              hipStream_t stream) {
    const float* x           = (const float*)d_in[0];
    const float* w_qkv       = (const float*)d_in[1];
    const float* w_dw        = (const float*)d_in[2];
    const float* ln_g        = (const float*)d_in[3];
    const float* ln_b        = (const float*)d_in[4];
    const float* q_bias      = (const float*)d_in[5];
    const float* v_bias      = (const float*)d_in[6];
    const float* logit_scale = (const float*)d_in[7];
    const float* cpb_w1      = (const float*)d_in[8];
    const float* cpb_b1      = (const float*)d_in[9];
    const float* cpb_w2      = (const float*)d_in[10];
    const float* w_proj      = (const float*)d_in[11];
    float* out = (float*)d_out;

    char* ws = (char*)d_ws;
    _Float16* qkv0h  = (_Float16*)(ws);                          // 50.33 MB
    _Float16* qkvh   = (_Float16*)(ws + 50331648);               // 50.33 MB
    _Float16* attnh  = (_Float16*)(ws + 100663296);              // 16.78 MB
    _Float16* wqkvT  = (_Float16*)(ws + 117440512);              // 0.39 MB
    _Float16* wprojT = (_Float16*)(ws + 117833728);              // 0.13 MB
    _Float16* wdwh   = (_Float16*)(ws + 117964800);              // 13.8 KB
    float*    btab   = (float*)   (ws + 117981184);              // 17 KB

    cpb_kernel<<<529, 64, 0, stream>>>(cpb_w1, cpb_b1, cpb_w2, btab);
    cvt_wdw<<<27, 256, 0, stream>>>(w_dw, wdwh);
    transpose_cvt<<<dim3(C3 / 32, CC / 32), 256, 0, stream>>>(w_qkv, wqkvT, CC, C3);
    transpose_cvt<<<dim3(CC / 32, CC / 32), 256, 0, stream>>>(w_proj, wprojT, CC, CC);

    // qkv0 = x @ w_qkv    (fused fp32->fp16 A convert)
    gemm_qkv<<<dim3(C3 / 128, NPIX / 128), 256, 0, stream>>>(
        x, wqkvT, qkv0h, NPIX, C3, CC);
    // depthwise 3x3 + LN + bias  (8-pixel strips; v third -> bf16 bits)
    dwconv_ln<<<NPIX / 8, 256, 0, stream>>>(qkv0h, wdwh, ln_g, ln_b, q_bias,
                                            v_bias, qkvh);
    // halo window attention
    attn_mfma<<<NWIN * NHEADS, 256, 0, stream>>>(qkvh, btab, logit_scale, attnh);
    // out = attn_out @ w_proj   (fp32 out)
    gemm_f16<float><<<dim3(CC / 128, NPIX / 128), 256, 0, stream>>>(
        attnh, wprojT, out, NPIX, CC, CC);
}